// Round 16
// baseline (3121.845 us; speedup 1.0000x reference)
//
#include <hip/hip_runtime.h>
#include <hip/hip_bf16.h>
#include <math.h>

#define E_DIM 1024
#define T_SEQ 2048
#define NH 16
#define DHEAD 64
#define NB 4
#define NLAYER 8

typedef __attribute__((ext_vector_type(8))) short bf16x8;
typedef __attribute__((ext_vector_type(4))) short short4v;
typedef __attribute__((ext_vector_type(4))) float f32x4;

#if __has_builtin(__builtin_amdgcn_exp2f)
#define EXP2(x) __builtin_amdgcn_exp2f(x)
#else
#define EXP2(x) exp2f(x)
#endif

static __device__ __forceinline__ short f2bf(float f) {
  union { __hip_bfloat16 h; short s; } u;
  u.h = __float2bfloat16(f);
  return u.s;
}
static __device__ __forceinline__ float bf2f(short s) {
  union { unsigned u; float f; } v;
  v.u = ((unsigned)(unsigned short)s) << 16;
  return v.f;
}

// async global->LDS, 16B per lane; LDS dest is wave-uniform base + lane*16.
static __device__ __forceinline__ void gload16(const short* g, short* l) {
  __builtin_amdgcn_global_load_lds(
      (const __attribute__((address_space(1))) unsigned*)(g),
      (__attribute__((address_space(3))) unsigned*)(l), 16, 0, 0);
}

// XCD-aware bijective block swizzle (valid when nwg % 8 == 0).
static __device__ __forceinline__ int xcd_swz(int orig, int nwg) {
  return (orig & 7) * (nwg >> 3) + (orig >> 3);
}

// ============================ embedding (f32) ============================
__global__ __launch_bounds__(256) void embed_kernel(const int* __restrict__ tokens,
    const float* __restrict__ emb, const float* __restrict__ pos, float* __restrict__ x) {
  int idx = blockIdx.x * 256 + threadIdx.x;
  int bt = idx >> 10;
  int e  = idx & 1023;
  int t  = bt & (T_SEQ - 1);
  int tok = tokens[bt];
  x[idx] = emb[tok * E_DIM + e] + pos[t * E_DIM + e];
}

// ============================ layernorm f32 -> bf16 ============================
__global__ __launch_bounds__(256) void ln_bf16_kernel(const float* __restrict__ x,
    const float* __restrict__ g, const float* __restrict__ b, short* __restrict__ out) {
  __shared__ float s1[4], s2[4];
  int row = blockIdx.x;
  const float4* xr = (const float4*)(x + (size_t)row * E_DIM);
  float4 xv = xr[threadIdx.x];
  float s = xv.x + xv.y + xv.z + xv.w;
  float q = xv.x*xv.x + xv.y*xv.y + xv.z*xv.z + xv.w*xv.w;
  #pragma unroll
  for (int off = 32; off; off >>= 1) {
    s += __shfl_xor(s, off, 64);
    q += __shfl_xor(q, off, 64);
  }
  int lane = threadIdx.x & 63, wid = threadIdx.x >> 6;
  if (lane == 0) { s1[wid] = s; s2[wid] = q; }
  __syncthreads();
  float mean = (s1[0] + s1[1] + s1[2] + s1[3]) * (1.0f / E_DIM);
  float ms   = (s2[0] + s2[1] + s2[2] + s2[3]) * (1.0f / E_DIM);
  float rstd = rsqrtf(ms - mean * mean + 1e-5f);
  float4 gv = ((const float4*)g)[threadIdx.x];
  float4 bv = ((const float4*)b)[threadIdx.x];
  short4v ov;
  ov.x = f2bf((xv.x - mean) * rstd * gv.x + bv.x);
  ov.y = f2bf((xv.y - mean) * rstd * gv.y + bv.y);
  ov.z = f2bf((xv.z - mean) * rstd * gv.z + bv.z);
  ov.w = f2bf((xv.w - mean) * rstd * gv.w + bv.w);
  *(short4v*)(out + (size_t)row * E_DIM + threadIdx.x * 4) = ov;
}

// ============================ merged per-layer weight prep ============================
struct PrepP {
  const float *s0, *s1, *s2, *s3, *s4, *s5;
  short *d0, *d1, *d2, *d3, *d4, *d5;
};

__global__ void prep_kernel(PrepP p) {
  __shared__ float tile[32][33];
  int bid = blockIdx.x;
  const float* src; short* dst; int K, N, kb, local;
  if (bid < 1024)      { src = p.s0; dst = p.d0; K = 1024; N = 64;   kb = 32;  local = bid; }
  else if (bid < 2048) { src = p.s1; dst = p.d1; K = 1024; N = 64;   kb = 32;  local = bid - 1024; }
  else if (bid < 3072) { src = p.s2; dst = p.d2; K = 1024; N = 64;   kb = 32;  local = bid - 2048; }
  else if (bid < 4096) { src = p.s3; dst = p.d3; K = 1024; N = 1024; kb = 32;  local = bid - 3072; }
  else if (bid < 8192) { src = p.s4; dst = p.d4; K = 1024; N = 4096; kb = 32;  local = bid - 4096; }
  else                 { src = p.s5; dst = p.d5; K = 4096; N = 1024; kb = 128; local = bid - 8192; }
  int per = kb * (N >> 5);
  int z = local / per, rem = local % per;
  int k0 = (rem % kb) * 32, n0 = (rem / kb) * 32;
  src += (size_t)z * K * N;
  dst += (size_t)z * N * K;
  int tx = threadIdx.x, ty = threadIdx.y;
  #pragma unroll
  for (int i = 0; i < 4; ++i)
    tile[ty + 8 * i][tx] = src[(size_t)(k0 + ty + 8 * i) * N + n0 + tx];
  __syncthreads();
  #pragma unroll
  for (int i = 0; i < 4; ++i)
    dst[(size_t)(n0 + ty + 8 * i) * K + k0 + tx] = f2bf(tile[tx][ty + 8 * i]);
}

// ============================ bf16 MFMA GEMM: 128x256, tri-buffer, counted vmcnt(6) ============================
// (round-10 structure — best verified)
struct GemmP {
  const short* A; const short* B; void* C;
  const float* bias; const float* res;
  long sAb, sAt, sAh;       // m>>11, m&2047, k>>6 (k&63 stride 1)
  long sBh, sBd;            // n>>6, n&63 (k stride 1)
  long sCb, sCt, sCh;       // m>>11, m&2047, n>>6 (n&63 stride 1)
  int K; float alpha; int alphaN; int gridx;
  int relu; int cbf16; int hasbias; int hasres;
};

__global__ __launch_bounds__(512, 1) void gemm_bf16(GemmP p) {
  extern __shared__ __align__(16) short Lsh[];
  constexpr int ASZ  = 128 * 64;          // 8192 shorts (16KB)
  constexpr int SLOT = ASZ + 256 * 64;    // + 16384 shorts (32KB) = 48KB/slot

  const int t = threadIdx.x;
  const int lane = t & 63, wid = t >> 6;
  const int wm = wid >> 2, wn = wid & 3;
  const int rA = lane & 15, g = lane >> 4;
  const int wg = xcd_swz(blockIdx.x, gridDim.x);
  const long bm = (long)(wg / p.gridx) * 128, bn = (long)(wg % p.gridx) * 256;

  const int srow8 = lane >> 3;
  const int schunk = (lane & 7) ^ srow8;
  const short* aS[2]; const short* bS[4];
  #pragma unroll
  for (int i = 0; i < 2; ++i) {
    long m = bm + i * 64 + wid * 8 + srow8;
    aS[i] = p.A + (m >> 11) * p.sAb + (m & 2047) * p.sAt + schunk * 8;
  }
  #pragma unroll
  for (int i = 0; i < 4; ++i) {
    long n = bn + i * 64 + wid * 8 + srow8;
    bS[i] = p.B + (n >> 6) * p.sBh + (n & 63) * p.sBd + schunk * 8;
  }
  const int dOff = wid * 512;

#define ISSUE_TILE(slot)                                                      \
  {                                                                           \
    short* sb = Lsh + (slot) * SLOT;                                          \
    _Pragma("unroll")                                                         \
    for (int i = 0; i < 2; ++i) { gload16(aS[i], sb + i * 4096 + dOff); aS[i] += p.sAh; } \
    _Pragma("unroll")                                                         \
    for (int i = 0; i < 4; ++i) { gload16(bS[i], sb + ASZ + i * 4096 + dOff); bS[i] += 64; } \
  }

  f32x4 acc[4][4] = {};
  const int NT = p.K >> 6;

  ISSUE_TILE(0)
  ISSUE_TILE(1)
  asm volatile("s_waitcnt vmcnt(6)" ::: "memory");
  __builtin_amdgcn_s_barrier();

  int rd = 0;
  for (int kt = 0; kt < NT; ++kt) {
    const int wr2 = rd + 2 >= 3 ? rd - 1 : rd + 2;
    if (kt + 2 < NT) ISSUE_TILE(wr2)
    const short* sb = Lsh + rd * SLOT;
    bf16x8 af[4][2], bf[4][2];
    #pragma unroll
    for (int kk = 0; kk < 2; ++kk) {
      const int ch = ((g + kk * 4) ^ (rA & 7)) * 8;
      #pragma unroll
      for (int f = 0; f < 4; ++f) {
        af[f][kk] = *(const bf16x8*)&sb[(wm * 64 + f * 16 + rA) * 64 + ch];
        bf[f][kk] = *(const bf16x8*)&sb[ASZ + (wn * 64 + f * 16 + rA) * 64 + ch];
      }
    }
    asm volatile("s_waitcnt lgkmcnt(0)" ::: "memory");
    __builtin_amdgcn_sched_barrier(0);
    __builtin_amdgcn_s_setprio(1);
    #pragma unroll
    for (int kk = 0; kk < 2; ++kk)
      #pragma unroll
      for (int i = 0; i < 4; ++i)
        #pragma unroll
        for (int j = 0; j < 4; ++j)
          acc[i][j] = __builtin_amdgcn_mfma_f32_16x16x32_bf16(af[i][kk], bf[j][kk], acc[i][j], 0, 0, 0);
    __builtin_amdgcn_s_setprio(0);
    if (kt + 1 < NT) {
      if (kt + 2 < NT) { asm volatile("s_waitcnt vmcnt(6)" ::: "memory"); }
      else             { asm volatile("s_waitcnt vmcnt(0)" ::: "memory"); }
      __builtin_amdgcn_s_barrier();
    }
    rd = rd + 1 >= 3 ? 0 : rd + 1;
  }
#undef ISSUE_TILE

  float bias4[4], aa4[4];
  long ncol[4];
  #pragma unroll
  for (int j = 0; j < 4; ++j) {
    long n = bn + wn * 64 + j * 16 + rA;
    ncol[j] = (n >> 6) * p.sCh + (n & 63);
    bias4[j] = p.hasbias ? p.bias[n] : 0.f;
    aa4[j] = (n < p.alphaN) ? p.alpha : 1.0f;
  }
  #pragma unroll
  for (int i = 0; i < 4; ++i) {
    #pragma unroll
    for (int r = 0; r < 4; ++r) {
      long m = bm + wm * 64 + i * 16 + g * 4 + r;
      long mb = (m >> 11) * p.sCb + (m & 2047) * p.sCt;
      #pragma unroll
      for (int j = 0; j < 4; ++j) {
        long ca = mb + ncol[j];
        float v = aa4[j] * acc[i][j][r] + bias4[j];
        if (p.relu) v = fmaxf(v, 0.f);
        if (p.hasres) v += p.res[ca];
        if (p.cbf16) ((short*)p.C)[ca] = f2bf(v);
        else ((float*)p.C)[ca] = v;
      }
    }
  }
}

// ============================ MFMA flash attention v5c ============================
// v5b + HW packed bf16 conversion, FIXED: one asm block, both outputs
// early-clobbered ("=&v") so the pack registers can never alias e2/e3 —
// r11's failure was exactly that aliasing (two separate asm stmts, no "&").
// v_cvt_pk_bf16_f32 packs src0->low16, src1->high16 (little-endian short order).
__global__ __launch_bounds__(512) void attn_mfma_kernel(const short* __restrict__ qkv,
                                                        short* __restrict__ att) {
  __shared__ __align__(16) short Ks[64 * 64];
  __shared__ __align__(16) short Vt[64 * 64];
  __shared__ __align__(16) short Pq[8 * 16 * 64];

  const int t = threadIdx.x;
  const int lane = t & 63, wid = t >> 6;
  const int wg = xcd_swz(blockIdx.x, gridDim.x);
  const int bh = wg >> 4;
  const int b = bh >> 4, h = bh & 15;
  const int q0blk = (wg & 15) * 128;
  const int rA = lane & 15;
  const int g  = lane >> 4;
  const int xq = (rA & 7) << 3;
  const float L2E = 1.4426950408889634f;

  const short* Qg = qkv + (size_t)b * 6291456 + (size_t)h * 131072;
  const short* Kg = Qg + 2097152;
  const short* Vg = Qg + 4194304;

  const int q0w = q0blk + wid * 16;
  bf16x8 qf0 = *(const bf16x8*)(Qg + (size_t)(q0w + rA) * DHEAD + g * 8);
  bf16x8 qf1 = *(const bf16x8*)(Qg + (size_t)(q0w + rA) * DHEAD + 32 + g * 8);

  bf16x8 ones;
  #pragma unroll
  for (int j = 0; j < 8; ++j) ones[j] = (short)0x3F80;   // bf16 1.0

  short* Pw = Pq + wid * 1024;
  const int ss = t >> 3, sp = t & 7;

  f32x4 lrun4 = {};             // denominator for q = g*4+r (acco layout, ones-MFMA)
  f32x4 acco[4] = {};

  bf16x8 kreg = *(const bf16x8*)(Kg + (size_t)ss * DHEAD + sp * 8);
  bf16x8 vreg = *(const bf16x8*)(Vg + (size_t)ss * DHEAD + sp * 8);

  for (int tile = 0; tile < T_SEQ / 64; ++tile) {
    __syncthreads();
    *(bf16x8*)&Ks[ss * 64 + ((sp ^ (ss & 7)) << 3)] = kreg;
    #pragma unroll
    for (int j = 0; j < 8; ++j) {
      int d = sp * 8 + j;
      Vt[d * 64 + ((ss + 8 * (sp + j)) & 63)] = vreg[j];
    }
    __syncthreads();
    if (tile + 1 < T_SEQ / 64) {
      kreg = *(const bf16x8*)(Kg + (size_t)((tile + 1) * 64 + ss) * DHEAD + sp * 8);
      vreg = *(const bf16x8*)(Vg + (size_t)((tile + 1) * 64 + ss) * DHEAD + sp * 8);
    }

    // ---- QK^T: S^T[s][q] (Q pre-scaled by 1/sqrt(T)) ----
    f32x4 accs[4];
    __builtin_amdgcn_s_setprio(1);
    #pragma unroll
    for (int st = 0; st < 4; ++st) {
      int srow = st * 16 + rA;
      bf16x8 kf0 = *(const bf16x8*)&Ks[srow * 64 + ((g ^ (rA & 7)) << 3)];
      bf16x8 kf1 = *(const bf16x8*)&Ks[srow * 64 + (((g + 4) ^ (rA & 7)) << 3)];
      f32x4 z = {};
      z = __builtin_amdgcn_mfma_f32_16x16x32_bf16(kf0, qf0, z, 0, 0, 0);
      accs[st] = __builtin_amdgcn_mfma_f32_16x16x32_bf16(kf1, qf1, z, 0, 0, 0);
    }
    __builtin_amdgcn_s_setprio(0);

    // ---- no-max softmax numerators -> packed bf16 (cvt_pk, early-clobbered) ----
    #pragma unroll
    for (int st = 0; st < 4; ++st) {
      float e0 = EXP2(accs[st][0] * L2E);
      float e1 = EXP2(accs[st][1] * L2E);
      float e2 = EXP2(accs[st][2] * L2E);
      float e3 = EXP2(accs[st][3] * L2E);
      unsigned w0, w1;
      asm("v_cvt_pk_bf16_f32 %0, %2, %3\n\t"
          "v_cvt_pk_bf16_f32 %1, %4, %5"
          : "=&v"(w0), "=&v"(w1)
          : "v"(e0), "v"(e1), "v"(e2), "v"(e3));
      uint2 pk; pk.x = w0; pk.y = w1;
      *(uint2*)&Pw[(rA * 64 + st * 16 + g * 4) ^ xq] = pk;
    }
    asm volatile("s_waitcnt lgkmcnt(0)" ::: "memory");

    // ---- PV (+ ones-MFMA accumulates the denominator on the matrix pipe) ----
    __builtin_amdgcn_s_setprio(1);
    #pragma unroll
    for (int sk = 0; sk < 2; ++sk) {
      bf16x8 pf = *(const bf16x8*)&Pw[(rA * 64 + sk * 32 + g * 8) ^ xq];
      lrun4 = __builtin_amdgcn_mfma_f32_16x16x32_bf16(pf, ones, lrun4, 0, 0, 0);
      #pragma unroll
      for (int dt = 0; dt < 4; ++dt) {
        int d = dt * 16 + rA;
        bf16x8 vf = *(const bf16x8*)&Vt[d * 64 +
            ((sk * 32 + g * 8 + 8 * (dt * 2 + (rA >> 3) + (rA & 7))) & 63)];
        acco[dt] = __builtin_amdgcn_mfma_f32_16x16x32_bf16(pf, vf, acco[dt], 0, 0, 0);
      }
    }
    __builtin_amdgcn_s_setprio(0);
  }

  float l4[4];
  #pragma unroll
  for (int r = 0; r < 4; ++r) l4[r] = 1.0f / lrun4[r];
  #pragma unroll
  for (int dt = 0; dt < 4; ++dt)
    #pragma unroll
    for (int r = 0; r < 4; ++r)
      att[(size_t)bh * T_SEQ * DHEAD + (size_t)(q0w + g * 4 + r) * DHEAD + dt * 16 + rA] =
          f2bf(acco[dt][r] * l4[r]);
}

// ============================ head ============================
__global__ __launch_bounds__(256) void head_kernel(const short* __restrict__ h,
    const float* __restrict__ Wu, const float* __restrict__ bu, float* __restrict__ out) {
  __shared__ float sm[8];
  int row = blockIdx.x;
  const short* hr = h + (size_t)row * E_DIM;
  float a0 = 0.f, a1 = 0.f;
  for (int i = threadIdx.x; i < E_DIM; i += 256) {
    float hv = bf2f(hr[i]);
    a0 = fmaf(hv, Wu[i * 2 + 0], a0);
    a1 = fmaf(hv, Wu[i * 2 + 1], a1);
  }
  #pragma unroll
  for (int off = 32; off; off >>= 1) {
    a0 += __shfl_xor(a0, off, 64);
    a1 += __shfl_xor(a1, off, 64);
  }
  int lane = threadIdx.x & 63, wid = threadIdx.x >> 6;
  if (lane == 0) { sm[wid] = a0; sm[4 + wid] = a1; }
  __syncthreads();
  if (threadIdx.x == 0) {
    out[row * 2 + 0] = sm[0] + sm[1] + sm[2] + sm[3] + bu[0];
    out[row * 2 + 1] = sm[4] + sm[5] + sm[6] + sm[7] + bu[1];
  }
}

// ============================ launcher ============================
static inline void launch_gemm(hipStream_t stream, int N,
    const short* A, long sAb, long sAt, long sAh,
    const short* B, long sBh, long sBd,
    void* C, long sCb, long sCt, long sCh,
    const float* bias, const float* res, int K, float alpha, int alphaN,
    int relu, int cbf16) {
  GemmP p;
  p.A = A; p.B = B; p.C = C; p.bias = bias; p.res = res;
  p.sAb = sAb; p.sAt = sAt; p.sAh = sAh;
  p.sBh = sBh; p.sBd = sBd;
  p.sCb = sCb; p.sCt = sCt; p.sCh = sCh;
  p.K = K; p.alpha = alpha; p.alphaN = alphaN; p.gridx = N / 256;
  p.relu = relu; p.cbf16 = cbf16;
  p.hasbias = bias != nullptr; p.hasres = res != nullptr;
  int nwg = (N / 256) * ((NB * T_SEQ) / 128);
  gemm_bf16<<<nwg, 512, 147456, stream>>>(p);
}

extern "C" void kernel_launch(void* const* d_in, const int* in_sizes, int n_in,
                              void* d_out, int out_size, void* d_ws, size_t ws_size,
                              hipStream_t stream) {
  const int*   tokens = (const int*)d_in[0];
  const float* emb_w  = (const float*)d_in[1];
  const float* pos_w  = (const float*)d_in[2];
  const float* Wq     = (const float*)d_in[3];
  const float* Wk     = (const float*)d_in[4];
  const float* Wv     = (const float*)d_in[5];
  const float* Wo     = (const float*)d_in[6];
  const float* ln1_g  = (const float*)d_in[7];
  const float* ln1_b  = (const float*)d_in[8];
  const float* W1     = (const float*)d_in[9];
  const float* b1     = (const float*)d_in[10];
  const float* W2     = (const float*)d_in[11];
  const float* b2     = (const float*)d_in[12];
  const float* ln2_g  = (const float*)d_in[13];
  const float* ln2_b  = (const float*)d_in[14];
  const float* lnf_g  = (const float*)d_in[15];
  const float* lnf_b  = (const float*)d_in[16];
  const float* Wu     = (const float*)d_in[17];
  const float* bu     = (const float*)d_in[18];
  float* out = (float*)d_out;

  // ---- workspace layout (bytes) ----
  char* ws = (char*)d_ws;
  float* X     = (float*)(ws);                       // 32 MB f32 [B,T,E]
  short* Hb    = (short*)(ws + 33554432);            // 16 MB bf16 (LN out / attn out)
  short* QKVb  = (short*)(ws + 50331648);            // 48 MB bf16 [B][3][H][T][DH]
  short* FFH   = (short*)(ws + 100663296);           // 64 MB bf16 [8192,4096]
  short* WqkvT = (short*)(ws + 167772160);           // 6 MB  [3][16][64][1024]
  short* WoT   = (short*)(ws + 174063616);           // 2 MB  [1024][1024]
  short* W1T   = (short*)(ws + 176160768);           // 8 MB  [4096][1024]
  short* W2T   = (short*)(ws + 184549376);           // 8 MB  [1024][4096]

  const float scale = 0.022097086912079608f;         // 1/sqrt(2048)

  embed_kernel<<<32768, 256, 0, stream>>>(tokens, emb_w, pos_w, X);

  for (int l = 0; l < NLAYER; ++l) {
    PrepP pp;
    pp.s0 = Wq + (size_t)l * 1048576; pp.d0 = WqkvT;
    pp.s1 = Wk + (size_t)l * 1048576; pp.d1 = WqkvT + 1048576;
    pp.s2 = Wv + (size_t)l * 1048576; pp.d2 = WqkvT + 2097152;
    pp.s3 = Wo + (size_t)l * 1048576; pp.d3 = WoT;
    pp.s4 = W1 + (size_t)l * 4194304; pp.d4 = W1T;
    pp.s5 = W2 + (size_t)l * 4194304; pp.d5 = W2T;
    prep_kernel<<<12288, dim3(32, 8), 0, stream>>>(pp);

    ln_bf16_kernel<<<8192, 256, 0, stream>>>(X, ln1_g + l * 1024, ln1_b + l * 1024, Hb);

    // merged QKV: N = 3072, C -> [b][3][h][t][d]; Q cols pre-scaled
    launch_gemm(stream, 3072, Hb, 2097152, 1024, 64, WqkvT, 65536, 1024,
                QKVb, 6291456, 64, 131072, nullptr, nullptr, 1024, scale, 1024, 0, 1);

    attn_mfma_kernel<<<1024, 512, 0, stream>>>(QKVb, Hb);   // att -> Hb

    // Wo: A=att [B,H,T,DH], C=X f32 (+res X)
    launch_gemm(stream, 1024, Hb, 2097152, 64, 131072, WoT, 65536, 1024,
                X, 2097152, 1024, 64, nullptr, X, 1024, 1.0f, 0, 0, 0);

    ln_bf16_kernel<<<8192, 256, 0, stream>>>(X, ln2_g + l * 1024, ln2_b + l * 1024, Hb);

    launch_gemm(stream, 4096, Hb, 2097152, 1024, 64, W1T, 65536, 1024,
                FFH, 8388608, 4096, 64, b1 + (size_t)l * 4096, nullptr, 1024, 1.0f, 0, 1, 1);
    launch_gemm(stream, 1024, FFH, 8388608, 4096, 64, W2T, 262144, 4096,
                X, 2097152, 1024, 64, b2 + (size_t)l * 1024, X, 4096, 1.0f, 0, 0, 0);
  }

  ln_bf16_kernel<<<8192, 256, 0, stream>>>(X, lnf_g, lnf_b, Hb);
  head_kernel<<<8192, 256, 0, stream>>>(Hb, Wu, bu, out);
}

// Round 17
// 3115.929 us; speedup vs baseline: 1.0019x; 1.0019x over previous
//
#include <hip/hip_runtime.h>
#include <hip/hip_bf16.h>
#include <math.h>

#define E_DIM 1024
#define T_SEQ 2048
#define NH 16
#define DHEAD 64
#define NB 4
#define NLAYER 8

typedef __attribute__((ext_vector_type(8))) short bf16x8;
typedef __attribute__((ext_vector_type(4))) short short4v;
typedef __attribute__((ext_vector_type(4))) float f32x4;

#if __has_builtin(__builtin_amdgcn_exp2f)
#define EXP2(x) __builtin_amdgcn_exp2f(x)
#else
#define EXP2(x) exp2f(x)
#endif

static __device__ __forceinline__ short f2bf(float f) {
  union { __hip_bfloat16 h; short s; } u;
  u.h = __float2bfloat16(f);
  return u.s;
}
static __device__ __forceinline__ float bf2f(short s) {
  union { unsigned u; float f; } v;
  v.u = ((unsigned)(unsigned short)s) << 16;
  return v.f;
}

// async global->LDS, 16B per lane; LDS dest is wave-uniform base + lane*16.
static __device__ __forceinline__ void gload16(const short* g, short* l) {
  __builtin_amdgcn_global_load_lds(
      (const __attribute__((address_space(1))) unsigned*)(g),
      (__attribute__((address_space(3))) unsigned*)(l), 16, 0, 0);
}

// XCD-aware bijective block swizzle (valid when nwg % 8 == 0).
static __device__ __forceinline__ int xcd_swz(int orig, int nwg) {
  return (orig & 7) * (nwg >> 3) + (orig >> 3);
}

// ============================ embedding (f32) ============================
__global__ __launch_bounds__(256) void embed_kernel(const int* __restrict__ tokens,
    const float* __restrict__ emb, const float* __restrict__ pos, float* __restrict__ x) {
  int idx = blockIdx.x * 256 + threadIdx.x;
  int bt = idx >> 10;
  int e  = idx & 1023;
  int t  = bt & (T_SEQ - 1);
  int tok = tokens[bt];
  x[idx] = emb[tok * E_DIM + e] + pos[t * E_DIM + e];
}

// ============================ layernorm f32 -> bf16 ============================
__global__ __launch_bounds__(256) void ln_bf16_kernel(const float* __restrict__ x,
    const float* __restrict__ g, const float* __restrict__ b, short* __restrict__ out) {
  __shared__ float s1[4], s2[4];
  int row = blockIdx.x;
  const float4* xr = (const float4*)(x + (size_t)row * E_DIM);
  float4 xv = xr[threadIdx.x];
  float s = xv.x + xv.y + xv.z + xv.w;
  float q = xv.x*xv.x + xv.y*xv.y + xv.z*xv.z + xv.w*xv.w;
  #pragma unroll
  for (int off = 32; off; off >>= 1) {
    s += __shfl_xor(s, off, 64);
    q += __shfl_xor(q, off, 64);
  }
  int lane = threadIdx.x & 63, wid = threadIdx.x >> 6;
  if (lane == 0) { s1[wid] = s; s2[wid] = q; }
  __syncthreads();
  float mean = (s1[0] + s1[1] + s1[2] + s1[3]) * (1.0f / E_DIM);
  float ms   = (s2[0] + s2[1] + s2[2] + s2[3]) * (1.0f / E_DIM);
  float rstd = rsqrtf(ms - mean * mean + 1e-5f);
  float4 gv = ((const float4*)g)[threadIdx.x];
  float4 bv = ((const float4*)b)[threadIdx.x];
  short4v ov;
  ov.x = f2bf((xv.x - mean) * rstd * gv.x + bv.x);
  ov.y = f2bf((xv.y - mean) * rstd * gv.y + bv.y);
  ov.z = f2bf((xv.z - mean) * rstd * gv.z + bv.z);
  ov.w = f2bf((xv.w - mean) * rstd * gv.w + bv.w);
  *(short4v*)(out + (size_t)row * E_DIM + threadIdx.x * 4) = ov;
}

// ============================ merged per-layer weight prep ============================
struct PrepP {
  const float *s0, *s1, *s2, *s3, *s4, *s5;
  short *d0, *d1, *d2, *d3, *d4, *d5;
};

__global__ void prep_kernel(PrepP p) {
  __shared__ float tile[32][33];
  int bid = blockIdx.x;
  const float* src; short* dst; int K, N, kb, local;
  if (bid < 1024)      { src = p.s0; dst = p.d0; K = 1024; N = 64;   kb = 32;  local = bid; }
  else if (bid < 2048) { src = p.s1; dst = p.d1; K = 1024; N = 64;   kb = 32;  local = bid - 1024; }
  else if (bid < 3072) { src = p.s2; dst = p.d2; K = 1024; N = 64;   kb = 32;  local = bid - 2048; }
  else if (bid < 4096) { src = p.s3; dst = p.d3; K = 1024; N = 1024; kb = 32;  local = bid - 3072; }
  else if (bid < 8192) { src = p.s4; dst = p.d4; K = 1024; N = 4096; kb = 32;  local = bid - 4096; }
  else                 { src = p.s5; dst = p.d5; K = 4096; N = 1024; kb = 128; local = bid - 8192; }
  int per = kb * (N >> 5);
  int z = local / per, rem = local % per;
  int k0 = (rem % kb) * 32, n0 = (rem / kb) * 32;
  src += (size_t)z * K * N;
  dst += (size_t)z * N * K;
  int tx = threadIdx.x, ty = threadIdx.y;
  #pragma unroll
  for (int i = 0; i < 4; ++i)
    tile[ty + 8 * i][tx] = src[(size_t)(k0 + ty + 8 * i) * N + n0 + tx];
  __syncthreads();
  #pragma unroll
  for (int i = 0; i < 4; ++i)
    dst[(size_t)(n0 + ty + 8 * i) * K + k0 + tx] = f2bf(tile[tx][ty + 8 * i]);
}

// ============================ bf16 MFMA GEMM: 128x256, tri-buffer, counted vmcnt(6) ============================
// (round-10 structure — best verified: 8 waves (2/SIMD TLP), 3x48KB slots,
// counted waits never drain-0 in steady state, both-sides swizzle, 0 conflicts)
struct GemmP {
  const short* A; const short* B; void* C;
  const float* bias; const float* res;
  long sAb, sAt, sAh;       // m>>11, m&2047, k>>6 (k&63 stride 1)
  long sBh, sBd;            // n>>6, n&63 (k stride 1)
  long sCb, sCt, sCh;       // m>>11, m&2047, n>>6 (n&63 stride 1)
  int K; float alpha; int alphaN; int gridx;
  int relu; int cbf16; int hasbias; int hasres;
};

__global__ __launch_bounds__(512, 1) void gemm_bf16(GemmP p) {
  extern __shared__ __align__(16) short Lsh[];
  constexpr int ASZ  = 128 * 64;          // 8192 shorts (16KB)
  constexpr int SLOT = ASZ + 256 * 64;    // + 16384 shorts (32KB) = 48KB/slot

  const int t = threadIdx.x;
  const int lane = t & 63, wid = t >> 6;
  const int wm = wid >> 2, wn = wid & 3;
  const int rA = lane & 15, g = lane >> 4;
  const int wg = xcd_swz(blockIdx.x, gridDim.x);
  const long bm = (long)(wg / p.gridx) * 128, bn = (long)(wg % p.gridx) * 256;

  const int srow8 = lane >> 3;
  const int schunk = (lane & 7) ^ srow8;
  const short* aS[2]; const short* bS[4];
  #pragma unroll
  for (int i = 0; i < 2; ++i) {
    long m = bm + i * 64 + wid * 8 + srow8;
    aS[i] = p.A + (m >> 11) * p.sAb + (m & 2047) * p.sAt + schunk * 8;
  }
  #pragma unroll
  for (int i = 0; i < 4; ++i) {
    long n = bn + i * 64 + wid * 8 + srow8;
    bS[i] = p.B + (n >> 6) * p.sBh + (n & 63) * p.sBd + schunk * 8;
  }
  const int dOff = wid * 512;

#define ISSUE_TILE(slot)                                                      \
  {                                                                           \
    short* sb = Lsh + (slot) * SLOT;                                          \
    _Pragma("unroll")                                                         \
    for (int i = 0; i < 2; ++i) { gload16(aS[i], sb + i * 4096 + dOff); aS[i] += p.sAh; } \
    _Pragma("unroll")                                                         \
    for (int i = 0; i < 4; ++i) { gload16(bS[i], sb + ASZ + i * 4096 + dOff); bS[i] += 64; } \
  }

  f32x4 acc[4][4] = {};
  const int NT = p.K >> 6;

  ISSUE_TILE(0)
  ISSUE_TILE(1)
  asm volatile("s_waitcnt vmcnt(6)" ::: "memory");
  __builtin_amdgcn_s_barrier();

  int rd = 0;
  for (int kt = 0; kt < NT; ++kt) {
    const int wr2 = rd + 2 >= 3 ? rd - 1 : rd + 2;
    if (kt + 2 < NT) ISSUE_TILE(wr2)
    const short* sb = Lsh + rd * SLOT;
    bf16x8 af[4][2], bf[4][2];
    #pragma unroll
    for (int kk = 0; kk < 2; ++kk) {
      const int ch = ((g + kk * 4) ^ (rA & 7)) * 8;
      #pragma unroll
      for (int f = 0; f < 4; ++f) {
        af[f][kk] = *(const bf16x8*)&sb[(wm * 64 + f * 16 + rA) * 64 + ch];
        bf[f][kk] = *(const bf16x8*)&sb[ASZ + (wn * 64 + f * 16 + rA) * 64 + ch];
      }
    }
    asm volatile("s_waitcnt lgkmcnt(0)" ::: "memory");
    __builtin_amdgcn_sched_barrier(0);
    __builtin_amdgcn_s_setprio(1);
    #pragma unroll
    for (int kk = 0; kk < 2; ++kk)
      #pragma unroll
      for (int i = 0; i < 4; ++i)
        #pragma unroll
        for (int j = 0; j < 4; ++j)
          acc[i][j] = __builtin_amdgcn_mfma_f32_16x16x32_bf16(af[i][kk], bf[j][kk], acc[i][j], 0, 0, 0);
    __builtin_amdgcn_s_setprio(0);
    if (kt + 1 < NT) {
      if (kt + 2 < NT) { asm volatile("s_waitcnt vmcnt(6)" ::: "memory"); }
      else             { asm volatile("s_waitcnt vmcnt(0)" ::: "memory"); }
      __builtin_amdgcn_s_barrier();
    }
    rd = rd + 1 >= 3 ? 0 : rd + 1;
  }
#undef ISSUE_TILE

  float bias4[4], aa4[4];
  long ncol[4];
  #pragma unroll
  for (int j = 0; j < 4; ++j) {
    long n = bn + wn * 64 + j * 16 + rA;
    ncol[j] = (n >> 6) * p.sCh + (n & 63);
    bias4[j] = p.hasbias ? p.bias[n] : 0.f;
    aa4[j] = (n < p.alphaN) ? p.alpha : 1.0f;
  }
  #pragma unroll
  for (int i = 0; i < 4; ++i) {
    #pragma unroll
    for (int r = 0; r < 4; ++r) {
      long m = bm + wm * 64 + i * 16 + g * 4 + r;
      long mb = (m >> 11) * p.sCb + (m & 2047) * p.sCt;
      #pragma unroll
      for (int j = 0; j < 4; ++j) {
        long ca = mb + ncol[j];
        float v = aa4[j] * acc[i][j][r] + bias4[j];
        if (p.relu) v = fmaxf(v, 0.f);
        if (p.hasres) v += p.res[ca];
        if (p.cbf16) ((short*)p.C)[ca] = f2bf(v);
        else ((float*)p.C)[ca] = v;
      }
    }
  }
}

// ============================ MFMA flash attention v5b (best verified) ============================
__global__ __launch_bounds__(512) void attn_mfma_kernel(const short* __restrict__ qkv,
                                                        short* __restrict__ att) {
  __shared__ __align__(16) short Ks[64 * 64];
  __shared__ __align__(16) short Vt[64 * 64];
  __shared__ __align__(16) short Pq[8 * 16 * 64];

  const int t = threadIdx.x;
  const int lane = t & 63, wid = t >> 6;
  const int wg = xcd_swz(blockIdx.x, gridDim.x);
  const int bh = wg >> 4;
  const int b = bh >> 4, h = bh & 15;
  const int q0blk = (wg & 15) * 128;
  const int rA = lane & 15;
  const int g  = lane >> 4;
  const int xq = (rA & 7) << 3;
  const float L2E = 1.4426950408889634f;

  const short* Qg = qkv + (size_t)b * 6291456 + (size_t)h * 131072;
  const short* Kg = Qg + 2097152;
  const short* Vg = Qg + 4194304;

  const int q0w = q0blk + wid * 16;
  bf16x8 qf0 = *(const bf16x8*)(Qg + (size_t)(q0w + rA) * DHEAD + g * 8);
  bf16x8 qf1 = *(const bf16x8*)(Qg + (size_t)(q0w + rA) * DHEAD + 32 + g * 8);

  bf16x8 ones;
  #pragma unroll
  for (int j = 0; j < 8; ++j) ones[j] = (short)0x3F80;   // bf16 1.0

  short* Pw = Pq + wid * 1024;
  const int ss = t >> 3, sp = t & 7;

  f32x4 lrun4 = {};             // denominator for q = g*4+r (acco layout, ones-MFMA)
  f32x4 acco[4] = {};

  bf16x8 kreg = *(const bf16x8*)(Kg + (size_t)ss * DHEAD + sp * 8);
  bf16x8 vreg = *(const bf16x8*)(Vg + (size_t)ss * DHEAD + sp * 8);

  for (int tile = 0; tile < T_SEQ / 64; ++tile) {
    __syncthreads();
    *(bf16x8*)&Ks[ss * 64 + ((sp ^ (ss & 7)) << 3)] = kreg;
    #pragma unroll
    for (int j = 0; j < 8; ++j) {
      int d = sp * 8 + j;
      Vt[d * 64 + ((ss + 8 * (sp + j)) & 63)] = vreg[j];
    }
    __syncthreads();
    if (tile + 1 < T_SEQ / 64) {
      kreg = *(const bf16x8*)(Kg + (size_t)((tile + 1) * 64 + ss) * DHEAD + sp * 8);
      vreg = *(const bf16x8*)(Vg + (size_t)((tile + 1) * 64 + ss) * DHEAD + sp * 8);
    }

    // ---- QK^T: S^T[s][q] (Q pre-scaled by 1/sqrt(T)) ----
    f32x4 accs[4];
    __builtin_amdgcn_s_setprio(1);
    #pragma unroll
    for (int st = 0; st < 4; ++st) {
      int srow = st * 16 + rA;
      bf16x8 kf0 = *(const bf16x8*)&Ks[srow * 64 + ((g ^ (rA & 7)) << 3)];
      bf16x8 kf1 = *(const bf16x8*)&Ks[srow * 64 + (((g + 4) ^ (rA & 7)) << 3)];
      f32x4 z = {};
      z = __builtin_amdgcn_mfma_f32_16x16x32_bf16(kf0, qf0, z, 0, 0, 0);
      accs[st] = __builtin_amdgcn_mfma_f32_16x16x32_bf16(kf1, qf1, z, 0, 0, 0);
    }
    __builtin_amdgcn_s_setprio(0);

    // ---- no-max softmax numerators -> bf16 -> wave-private swizzled Pq ----
    #pragma unroll
    for (int st = 0; st < 4; ++st) {
      short4v pk;
      pk.x = f2bf(EXP2(accs[st][0] * L2E));
      pk.y = f2bf(EXP2(accs[st][1] * L2E));
      pk.z = f2bf(EXP2(accs[st][2] * L2E));
      pk.w = f2bf(EXP2(accs[st][3] * L2E));
      *(short4v*)&Pw[(rA * 64 + st * 16 + g * 4) ^ xq] = pk;
    }
    asm volatile("s_waitcnt lgkmcnt(0)" ::: "memory");

    // ---- PV (+ ones-MFMA accumulates the denominator on the matrix pipe) ----
    __builtin_amdgcn_s_setprio(1);
    #pragma unroll
    for (int sk = 0; sk < 2; ++sk) {
      bf16x8 pf = *(const bf16x8*)&Pw[(rA * 64 + sk * 32 + g * 8) ^ xq];
      lrun4 = __builtin_amdgcn_mfma_f32_16x16x32_bf16(pf, ones, lrun4, 0, 0, 0);
      #pragma unroll
      for (int dt = 0; dt < 4; ++dt) {
        int d = dt * 16 + rA;
        bf16x8 vf = *(const bf16x8*)&Vt[d * 64 +
            ((sk * 32 + g * 8 + 8 * (dt * 2 + (rA >> 3) + (rA & 7))) & 63)];
        acco[dt] = __builtin_amdgcn_mfma_f32_16x16x32_bf16(pf, vf, acco[dt], 0, 0, 0);
      }
    }
    __builtin_amdgcn_s_setprio(0);
  }

  float l4[4];
  #pragma unroll
  for (int r = 0; r < 4; ++r) l4[r] = 1.0f / lrun4[r];
  #pragma unroll
  for (int dt = 0; dt < 4; ++dt)
    #pragma unroll
    for (int r = 0; r < 4; ++r)
      att[(size_t)bh * T_SEQ * DHEAD + (size_t)(q0w + g * 4 + r) * DHEAD + dt * 16 + rA] =
          f2bf(acco[dt][r] * l4[r]);
}

// ============================ head ============================
__global__ __launch_bounds__(256) void head_kernel(const short* __restrict__ h,
    const float* __restrict__ Wu, const float* __restrict__ bu, float* __restrict__ out) {
  __shared__ float sm[8];
  int row = blockIdx.x;
  const short* hr = h + (size_t)row * E_DIM;
  float a0 = 0.f, a1 = 0.f;
  for (int i = threadIdx.x; i < E_DIM; i += 256) {
    float hv = bf2f(hr[i]);
    a0 = fmaf(hv, Wu[i * 2 + 0], a0);
    a1 = fmaf(hv, Wu[i * 2 + 1], a1);
  }
  #pragma unroll
  for (int off = 32; off; off >>= 1) {
    a0 += __shfl_xor(a0, off, 64);
    a1 += __shfl_xor(a1, off, 64);
  }
  int lane = threadIdx.x & 63, wid = threadIdx.x >> 6;
  if (lane == 0) { sm[wid] = a0; sm[4 + wid] = a1; }
  __syncthreads();
  if (threadIdx.x == 0) {
    out[row * 2 + 0] = sm[0] + sm[1] + sm[2] + sm[3] + bu[0];
    out[row * 2 + 1] = sm[4] + sm[5] + sm[6] + sm[7] + bu[1];
  }
}

// ============================ launcher ============================
static inline void launch_gemm(hipStream_t stream, int N,
    const short* A, long sAb, long sAt, long sAh,
    const short* B, long sBh, long sBd,
    void* C, long sCb, long sCt, long sCh,
    const float* bias, const float* res, int K, float alpha, int alphaN,
    int relu, int cbf16) {
  GemmP p;
  p.A = A; p.B = B; p.C = C; p.bias = bias; p.res = res;
  p.sAb = sAb; p.sAt = sAt; p.sAh = sAh;
  p.sBh = sBh; p.sBd = sBd;
  p.sCb = sCb; p.sCt = sCt; p.sCh = sCh;
  p.K = K; p.alpha = alpha; p.alphaN = alphaN; p.gridx = N / 256;
  p.relu = relu; p.cbf16 = cbf16;
  p.hasbias = bias != nullptr; p.hasres = res != nullptr;
  int nwg = (N / 256) * ((NB * T_SEQ) / 128);
  gemm_bf16<<<nwg, 512, 147456, stream>>>(p);
}

extern "C" void kernel_launch(void* const* d_in, const int* in_sizes, int n_in,
                              void* d_out, int out_size, void* d_ws, size_t ws_size,
                              hipStream_t stream) {
  const int*   tokens = (const int*)d_in[0];
  const float* emb_w  = (const float*)d_in[1];
  const float* pos_w  = (const float*)d_in[2];
  const float* Wq     = (const float*)d_in[3];
  const float* Wk     = (const float*)d_in[4];
  const float* Wv     = (const float*)d_in[5];
  const float* Wo     = (const float*)d_in[6];
  const float* ln1_g  = (const float*)d_in[7];
  const float* ln1_b  = (const float*)d_in[8];
  const float* W1     = (const float*)d_in[9];
  const float* b1     = (const float*)d_in[10];
  const float* W2     = (const float*)d_in[11];
  const float* b2     = (const float*)d_in[12];
  const float* ln2_g  = (const float*)d_in[13];
  const float* ln2_b  = (const float*)d_in[14];
  const float* lnf_g  = (const float*)d_in[15];
  const float* lnf_b  = (const float*)d_in[16];
  const float* Wu     = (const float*)d_in[17];
  const float* bu     = (const float*)d_in[18];
  float* out = (float*)d_out;

  // ---- workspace layout (bytes) ----
  char* ws = (char*)d_ws;
  float* X     = (float*)(ws);                       // 32 MB f32 [B,T,E]
  short* Hb    = (short*)(ws + 33554432);            // 16 MB bf16 (LN out / attn out)
  short* QKVb  = (short*)(ws + 50331648);            // 48 MB bf16 [B][3][H][T][DH]
  short* FFH   = (short*)(ws + 100663296);           // 64 MB bf16 [8192,4096]
  short* WqkvT = (short*)(ws + 167772160);           // 6 MB  [3][16][64][1024]
  short* WoT   = (short*)(ws + 174063616);           // 2 MB  [1024][1024]
  short* W1T   = (short*)(ws + 176160768);           // 8 MB  [4096][1024]
  short* W2T   = (short*)(ws + 184549376);           // 8 MB  [1024][4096]

  const float scale = 0.022097086912079608f;         // 1/sqrt(2048)

  embed_kernel<<<32768, 256, 0, stream>>>(tokens, emb_w, pos_w, X);

  for (int l = 0; l < NLAYER; ++l) {
    PrepP pp;
    pp.s0 = Wq + (size_t)l * 1048576; pp.d0 = WqkvT;
    pp.s1 = Wk + (size_t)l * 1048576; pp.d1 = WqkvT + 1048576;
    pp.s2 = Wv + (size_t)l * 1048576; pp.d2 = WqkvT + 2097152;
    pp.s3 = Wo + (size_t)l * 1048576; pp.d3 = WoT;
    pp.s4 = W1 + (size_t)l * 4194304; pp.d4 = W1T;
    pp.s5 = W2 + (size_t)l * 4194304; pp.d5 = W2T;
    prep_kernel<<<12288, dim3(32, 8), 0, stream>>>(pp);

    ln_bf16_kernel<<<8192, 256, 0, stream>>>(X, ln1_g + l * 1024, ln1_b + l * 1024, Hb);

    // merged QKV: N = 3072, C -> [b][3][h][t][d]; Q cols pre-scaled
    launch_gemm(stream, 3072, Hb, 2097152, 1024, 64, WqkvT, 65536, 1024,
                QKVb, 6291456, 64, 131072, nullptr, nullptr, 1024, scale, 1024, 0, 1);

    attn_mfma_kernel<<<1024, 512, 0, stream>>>(QKVb, Hb);   // att -> Hb

    // Wo: A=att [B,H,T,DH], C=X f32 (+res X)
    launch_gemm(stream, 1024, Hb, 2097152, 64, 131072, WoT, 65536, 1024,
                X, 2097152, 1024, 64, nullptr, X, 1024, 1.0f, 0, 0, 0);

    ln_bf16_kernel<<<8192, 256, 0, stream>>>(X, ln2_g + l * 1024, ln2_b + l * 1024, Hb);

    launch_gemm(stream, 4096, Hb, 2097152, 1024, 64, W1T, 65536, 1024,
                FFH, 8388608, 4096, 64, b1 + (size_t)l * 4096, nullptr, 1024, 1.0f, 0, 1, 1);
    launch_gemm(stream, 1024, FFH, 8388608, 4096, 64, W2T, 262144, 4096,
                X, 2097152, 1024, 64, b2 + (size_t)l * 1024, X, 4096, 1.0f, 0, 0, 0);
  }

  ln_bf16_kernel<<<8192, 256, 0, stream>>>(X, lnf_g, lnf_b, Hb);
  head_kernel<<<8192, 256, 0, stream>>>(Hb, Wu, bu, out);
}

// Round 18
// 3046.333 us; speedup vs baseline: 1.0248x; 1.0228x over previous
//
#include <hip/hip_runtime.h>
#include <hip/hip_bf16.h>
#include <math.h>

#define E_DIM 1024
#define T_SEQ 2048
#define NH 16
#define DHEAD 64
#define NB 4
#define NLAYER 8

typedef __attribute__((ext_vector_type(8))) short bf16x8;
typedef __attribute__((ext_vector_type(4))) short short4v;
typedef __attribute__((ext_vector_type(4))) float f32x4;

#if __has_builtin(__builtin_amdgcn_exp2f)
#define EXP2(x) __builtin_amdgcn_exp2f(x)
#else
#define EXP2(x) exp2f(x)
#endif

static __device__ __forceinline__ short f2bf(float f) {
  union { __hip_bfloat16 h; short s; } u;
  u.h = __float2bfloat16(f);
  return u.s;
}
static __device__ __forceinline__ float bf2f(short s) {
  union { unsigned u; float f; } v;
  v.u = ((unsigned)(unsigned short)s) << 16;
  return v.f;
}

// async global->LDS, 16B per lane; LDS dest is wave-uniform base + lane*16.
static __device__ __forceinline__ void gload16(const short* g, short* l) {
  __builtin_amdgcn_global_load_lds(
      (const __attribute__((address_space(1))) unsigned*)(g),
      (__attribute__((address_space(3))) unsigned*)(l), 16, 0, 0);
}

// XCD-aware bijective block swizzle (valid when nwg % 8 == 0).
static __device__ __forceinline__ int xcd_swz(int orig, int nwg) {
  return (orig & 7) * (nwg >> 3) + (orig >> 3);
}

// ============================ embedding (f32) ============================
__global__ __launch_bounds__(256) void embed_kernel(const int* __restrict__ tokens,
    const float* __restrict__ emb, const float* __restrict__ pos, float* __restrict__ x) {
  int idx = blockIdx.x * 256 + threadIdx.x;
  int bt = idx >> 10;
  int e  = idx & 1023;
  int t  = bt & (T_SEQ - 1);
  int tok = tokens[bt];
  x[idx] = emb[tok * E_DIM + e] + pos[t * E_DIM + e];
}

// ============================ layernorm f32 -> bf16 ============================
__global__ __launch_bounds__(256) void ln_bf16_kernel(const float* __restrict__ x,
    const float* __restrict__ g, const float* __restrict__ b, short* __restrict__ out) {
  __shared__ float s1[4], s2[4];
  int row = blockIdx.x;
  const float4* xr = (const float4*)(x + (size_t)row * E_DIM);
  float4 xv = xr[threadIdx.x];
  float s = xv.x + xv.y + xv.z + xv.w;
  float q = xv.x*xv.x + xv.y*xv.y + xv.z*xv.z + xv.w*xv.w;
  #pragma unroll
  for (int off = 32; off; off >>= 1) {
    s += __shfl_xor(s, off, 64);
    q += __shfl_xor(q, off, 64);
  }
  int lane = threadIdx.x & 63, wid = threadIdx.x >> 6;
  if (lane == 0) { s1[wid] = s; s2[wid] = q; }
  __syncthreads();
  float mean = (s1[0] + s1[1] + s1[2] + s1[3]) * (1.0f / E_DIM);
  float ms   = (s2[0] + s2[1] + s2[2] + s2[3]) * (1.0f / E_DIM);
  float rstd = rsqrtf(ms - mean * mean + 1e-5f);
  float4 gv = ((const float4*)g)[threadIdx.x];
  float4 bv = ((const float4*)b)[threadIdx.x];
  short4v ov;
  ov.x = f2bf((xv.x - mean) * rstd * gv.x + bv.x);
  ov.y = f2bf((xv.y - mean) * rstd * gv.y + bv.y);
  ov.z = f2bf((xv.z - mean) * rstd * gv.z + bv.z);
  ov.w = f2bf((xv.w - mean) * rstd * gv.w + bv.w);
  *(short4v*)(out + (size_t)row * E_DIM + threadIdx.x * 4) = ov;
}

// ============================ merged per-layer weight prep ============================
struct PrepP {
  const float *s0, *s1, *s2, *s3, *s4, *s5;
  short *d0, *d1, *d2, *d3, *d4, *d5;
};

__global__ void prep_kernel(PrepP p) {
  __shared__ float tile[32][33];
  int bid = blockIdx.x;
  const float* src; short* dst; int K, N, kb, local;
  if (bid < 1024)      { src = p.s0; dst = p.d0; K = 1024; N = 64;   kb = 32;  local = bid; }
  else if (bid < 2048) { src = p.s1; dst = p.d1; K = 1024; N = 64;   kb = 32;  local = bid - 1024; }
  else if (bid < 3072) { src = p.s2; dst = p.d2; K = 1024; N = 64;   kb = 32;  local = bid - 2048; }
  else if (bid < 4096) { src = p.s3; dst = p.d3; K = 1024; N = 1024; kb = 32;  local = bid - 3072; }
  else if (bid < 8192) { src = p.s4; dst = p.d4; K = 1024; N = 4096; kb = 32;  local = bid - 4096; }
  else                 { src = p.s5; dst = p.d5; K = 4096; N = 1024; kb = 128; local = bid - 8192; }
  int per = kb * (N >> 5);
  int z = local / per, rem = local % per;
  int k0 = (rem % kb) * 32, n0 = (rem / kb) * 32;
  src += (size_t)z * K * N;
  dst += (size_t)z * N * K;
  int tx = threadIdx.x, ty = threadIdx.y;
  #pragma unroll
  for (int i = 0; i < 4; ++i)
    tile[ty + 8 * i][tx] = src[(size_t)(k0 + ty + 8 * i) * N + n0 + tx];
  __syncthreads();
  #pragma unroll
  for (int i = 0; i < 4; ++i)
    dst[(size_t)(n0 + ty + 8 * i) * K + k0 + tx] = f2bf(tile[tx][ty + 8 * i]);
}

// ============================ bf16 MFMA GEMM: 128x256, tri-buffer, counted vmcnt(6) ============================
// (round-10 structure — frozen)
struct GemmP {
  const short* A; const short* B; void* C;
  const float* bias; const float* res;
  long sAb, sAt, sAh;       // m>>11, m&2047, k>>6 (k&63 stride 1)
  long sBh, sBd;            // n>>6, n&63 (k stride 1)
  long sCb, sCt, sCh;       // m>>11, m&2047, n>>6 (n&63 stride 1)
  int K; float alpha; int alphaN; int gridx;
  int relu; int cbf16; int hasbias; int hasres;
};

__global__ __launch_bounds__(512, 1) void gemm_bf16(GemmP p) {
  extern __shared__ __align__(16) short Lsh[];
  constexpr int ASZ  = 128 * 64;          // 8192 shorts (16KB)
  constexpr int SLOT = ASZ + 256 * 64;    // + 16384 shorts (32KB) = 48KB/slot

  const int t = threadIdx.x;
  const int lane = t & 63, wid = t >> 6;
  const int wm = wid >> 2, wn = wid & 3;
  const int rA = lane & 15, g = lane >> 4;
  const int wg = xcd_swz(blockIdx.x, gridDim.x);
  const long bm = (long)(wg / p.gridx) * 128, bn = (long)(wg % p.gridx) * 256;

  const int srow8 = lane >> 3;
  const int schunk = (lane & 7) ^ srow8;
  const short* aS[2]; const short* bS[4];
  #pragma unroll
  for (int i = 0; i < 2; ++i) {
    long m = bm + i * 64 + wid * 8 + srow8;
    aS[i] = p.A + (m >> 11) * p.sAb + (m & 2047) * p.sAt + schunk * 8;
  }
  #pragma unroll
  for (int i = 0; i < 4; ++i) {
    long n = bn + i * 64 + wid * 8 + srow8;
    bS[i] = p.B + (n >> 6) * p.sBh + (n & 63) * p.sBd + schunk * 8;
  }
  const int dOff = wid * 512;

#define ISSUE_TILE(slot)                                                      \
  {                                                                           \
    short* sb = Lsh + (slot) * SLOT;                                          \
    _Pragma("unroll")                                                         \
    for (int i = 0; i < 2; ++i) { gload16(aS[i], sb + i * 4096 + dOff); aS[i] += p.sAh; } \
    _Pragma("unroll")                                                         \
    for (int i = 0; i < 4; ++i) { gload16(bS[i], sb + ASZ + i * 4096 + dOff); bS[i] += 64; } \
  }

  f32x4 acc[4][4] = {};
  const int NT = p.K >> 6;

  ISSUE_TILE(0)
  ISSUE_TILE(1)
  asm volatile("s_waitcnt vmcnt(6)" ::: "memory");
  __builtin_amdgcn_s_barrier();

  int rd = 0;
  for (int kt = 0; kt < NT; ++kt) {
    const int wr2 = rd + 2 >= 3 ? rd - 1 : rd + 2;
    if (kt + 2 < NT) ISSUE_TILE(wr2)
    const short* sb = Lsh + rd * SLOT;
    bf16x8 af[4][2], bf[4][2];
    #pragma unroll
    for (int kk = 0; kk < 2; ++kk) {
      const int ch = ((g + kk * 4) ^ (rA & 7)) * 8;
      #pragma unroll
      for (int f = 0; f < 4; ++f) {
        af[f][kk] = *(const bf16x8*)&sb[(wm * 64 + f * 16 + rA) * 64 + ch];
        bf[f][kk] = *(const bf16x8*)&sb[ASZ + (wn * 64 + f * 16 + rA) * 64 + ch];
      }
    }
    asm volatile("s_waitcnt lgkmcnt(0)" ::: "memory");
    __builtin_amdgcn_sched_barrier(0);
    __builtin_amdgcn_s_setprio(1);
    #pragma unroll
    for (int kk = 0; kk < 2; ++kk)
      #pragma unroll
      for (int i = 0; i < 4; ++i)
        #pragma unroll
        for (int j = 0; j < 4; ++j)
          acc[i][j] = __builtin_amdgcn_mfma_f32_16x16x32_bf16(af[i][kk], bf[j][kk], acc[i][j], 0, 0, 0);
    __builtin_amdgcn_s_setprio(0);
    if (kt + 1 < NT) {
      if (kt + 2 < NT) { asm volatile("s_waitcnt vmcnt(6)" ::: "memory"); }
      else             { asm volatile("s_waitcnt vmcnt(0)" ::: "memory"); }
      __builtin_amdgcn_s_barrier();
    }
    rd = rd + 1 >= 3 ? 0 : rd + 1;
  }
#undef ISSUE_TILE

  float bias4[4], aa4[4];
  long ncol[4];
  #pragma unroll
  for (int j = 0; j < 4; ++j) {
    long n = bn + wn * 64 + j * 16 + rA;
    ncol[j] = (n >> 6) * p.sCh + (n & 63);
    bias4[j] = p.hasbias ? p.bias[n] : 0.f;
    aa4[j] = (n < p.alphaN) ? p.alpha : 1.0f;
  }
  #pragma unroll
  for (int i = 0; i < 4; ++i) {
    #pragma unroll
    for (int r = 0; r < 4; ++r) {
      long m = bm + wm * 64 + i * 16 + g * 4 + r;
      long mb = (m >> 11) * p.sCb + (m & 2047) * p.sCt;
      #pragma unroll
      for (int j = 0; j < 4; ++j) {
        long ca = mb + ncol[j];
        float v = aa4[j] * acc[i][j][r] + bias4[j];
        if (p.relu) v = fmaxf(v, 0.f);
        if (p.hasres) v += p.res[ca];
        if (p.cbf16) ((short*)p.C)[ca] = f2bf(v);
        else ((float*)p.C)[ca] = v;
      }
    }
  }
}

// ============================ MFMA flash attention v7: paired q-tiles ============================
// v5b + each wave owns TWO q-tiles (A: rows q0+wid*16, B: +128). Per KV tile the
// K/V fragments are read from LDS ONCE and feed both tiles' MFMAs (LDS reads per
// MFMA halve), and the two independent chains (QK^T_B fills softmax_A's stalls)
// give T15-style ILP. K/V global refetch also halves (grid 1024 -> 512 blocks).
__global__ __launch_bounds__(512) void attn_mfma_kernel(const short* __restrict__ qkv,
                                                        short* __restrict__ att) {
  __shared__ __align__(16) short Ks[64 * 64];
  __shared__ __align__(16) short Vt[64 * 64];
  __shared__ __align__(16) short Pq[8 * 2048];     // per wave: A at +0, B at +1024

  const int t = threadIdx.x;
  const int lane = t & 63, wid = t >> 6;
  const int wg = xcd_swz(blockIdx.x, gridDim.x);
  const int bh = wg >> 3;                   // 64 (b,h) groups, 8 q-blocks of 256
  const int b = bh >> 4, h = bh & 15;
  const int q0blk = (wg & 7) * 256;
  const int rA = lane & 15;
  const int g  = lane >> 4;
  const int xq = (rA & 7) << 3;
  const float L2E = 1.4426950408889634f;

  const short* Qg = qkv + (size_t)b * 6291456 + (size_t)h * 131072;
  const short* Kg = Qg + 2097152;
  const short* Vg = Qg + 4194304;

  const int qA = q0blk + wid * 16;
  const int qB = qA + 128;
  bf16x8 qfA0 = *(const bf16x8*)(Qg + (size_t)(qA + rA) * DHEAD + g * 8);
  bf16x8 qfA1 = *(const bf16x8*)(Qg + (size_t)(qA + rA) * DHEAD + 32 + g * 8);
  bf16x8 qfB0 = *(const bf16x8*)(Qg + (size_t)(qB + rA) * DHEAD + g * 8);
  bf16x8 qfB1 = *(const bf16x8*)(Qg + (size_t)(qB + rA) * DHEAD + 32 + g * 8);

  bf16x8 ones;
  #pragma unroll
  for (int j = 0; j < 8; ++j) ones[j] = (short)0x3F80;   // bf16 1.0

  short* PwA = Pq + wid * 2048;
  short* PwB = PwA + 1024;
  const int ss = t >> 3, sp = t & 7;

  f32x4 lrunA = {}, lrunB = {};
  f32x4 accoA[4] = {}, accoB[4] = {};

  bf16x8 kreg = *(const bf16x8*)(Kg + (size_t)ss * DHEAD + sp * 8);
  bf16x8 vreg = *(const bf16x8*)(Vg + (size_t)ss * DHEAD + sp * 8);

  for (int tile = 0; tile < T_SEQ / 64; ++tile) {
    __syncthreads();
    *(bf16x8*)&Ks[ss * 64 + ((sp ^ (ss & 7)) << 3)] = kreg;
    #pragma unroll
    for (int j = 0; j < 8; ++j) {
      int d = sp * 8 + j;
      Vt[d * 64 + ((ss + 8 * (sp + j)) & 63)] = vreg[j];
    }
    __syncthreads();
    if (tile + 1 < T_SEQ / 64) {
      kreg = *(const bf16x8*)(Kg + (size_t)((tile + 1) * 64 + ss) * DHEAD + sp * 8);
      vreg = *(const bf16x8*)(Vg + (size_t)((tile + 1) * 64 + ss) * DHEAD + sp * 8);
    }

    // ---- QK^T for both q-tiles; K fragments read once, used twice ----
    f32x4 accsA[4], accsB[4];
    __builtin_amdgcn_s_setprio(1);
    #pragma unroll
    for (int st = 0; st < 4; ++st) {
      int srow = st * 16 + rA;
      bf16x8 kf0 = *(const bf16x8*)&Ks[srow * 64 + ((g ^ (rA & 7)) << 3)];
      bf16x8 kf1 = *(const bf16x8*)&Ks[srow * 64 + (((g + 4) ^ (rA & 7)) << 3)];
      f32x4 zA = {}, zB = {};
      zA = __builtin_amdgcn_mfma_f32_16x16x32_bf16(kf0, qfA0, zA, 0, 0, 0);
      zB = __builtin_amdgcn_mfma_f32_16x16x32_bf16(kf0, qfB0, zB, 0, 0, 0);
      accsA[st] = __builtin_amdgcn_mfma_f32_16x16x32_bf16(kf1, qfA1, zA, 0, 0, 0);
      accsB[st] = __builtin_amdgcn_mfma_f32_16x16x32_bf16(kf1, qfB1, zB, 0, 0, 0);
    }
    __builtin_amdgcn_s_setprio(0);

    // ---- no-max softmax numerators, both tiles (independent chains) ----
    #pragma unroll
    for (int st = 0; st < 4; ++st) {
      short4v pkA;
      pkA.x = f2bf(EXP2(accsA[st][0] * L2E));
      pkA.y = f2bf(EXP2(accsA[st][1] * L2E));
      pkA.z = f2bf(EXP2(accsA[st][2] * L2E));
      pkA.w = f2bf(EXP2(accsA[st][3] * L2E));
      *(short4v*)&PwA[(rA * 64 + st * 16 + g * 4) ^ xq] = pkA;
      short4v pkB;
      pkB.x = f2bf(EXP2(accsB[st][0] * L2E));
      pkB.y = f2bf(EXP2(accsB[st][1] * L2E));
      pkB.z = f2bf(EXP2(accsB[st][2] * L2E));
      pkB.w = f2bf(EXP2(accsB[st][3] * L2E));
      *(short4v*)&PwB[(rA * 64 + st * 16 + g * 4) ^ xq] = pkB;
    }
    asm volatile("s_waitcnt lgkmcnt(0)" ::: "memory");

    // ---- PV for both tiles; V fragments read once, used twice ----
    __builtin_amdgcn_s_setprio(1);
    #pragma unroll
    for (int sk = 0; sk < 2; ++sk) {
      bf16x8 pfA = *(const bf16x8*)&PwA[(rA * 64 + sk * 32 + g * 8) ^ xq];
      bf16x8 pfB = *(const bf16x8*)&PwB[(rA * 64 + sk * 32 + g * 8) ^ xq];
      lrunA = __builtin_amdgcn_mfma_f32_16x16x32_bf16(pfA, ones, lrunA, 0, 0, 0);
      lrunB = __builtin_amdgcn_mfma_f32_16x16x32_bf16(pfB, ones, lrunB, 0, 0, 0);
      #pragma unroll
      for (int dt = 0; dt < 4; ++dt) {
        int d = dt * 16 + rA;
        bf16x8 vf = *(const bf16x8*)&Vt[d * 64 +
            ((sk * 32 + g * 8 + 8 * (dt * 2 + (rA >> 3) + (rA & 7))) & 63)];
        accoA[dt] = __builtin_amdgcn_mfma_f32_16x16x32_bf16(pfA, vf, accoA[dt], 0, 0, 0);
        accoB[dt] = __builtin_amdgcn_mfma_f32_16x16x32_bf16(pfB, vf, accoB[dt], 0, 0, 0);
      }
    }
    __builtin_amdgcn_s_setprio(0);
  }

  float lA[4], lB[4];
  #pragma unroll
  for (int r = 0; r < 4; ++r) { lA[r] = 1.0f / lrunA[r]; lB[r] = 1.0f / lrunB[r]; }
  const size_t obase = (size_t)bh * T_SEQ * DHEAD;
  #pragma unroll
  for (int dt = 0; dt < 4; ++dt)
    #pragma unroll
    for (int r = 0; r < 4; ++r) {
      att[obase + (size_t)(qA + g * 4 + r) * DHEAD + dt * 16 + rA] = f2bf(accoA[dt][r] * lA[r]);
      att[obase + (size_t)(qB + g * 4 + r) * DHEAD + dt * 16 + rA] = f2bf(accoB[dt][r] * lB[r]);
    }
}

// ============================ head ============================
__global__ __launch_bounds__(256) void head_kernel(const short* __restrict__ h,
    const float* __restrict__ Wu, const float* __restrict__ bu, float* __restrict__ out) {
  __shared__ float sm[8];
  int row = blockIdx.x;
  const short* hr = h + (size_t)row * E_DIM;
  float a0 = 0.f, a1 = 0.f;
  for (int i = threadIdx.x; i < E_DIM; i += 256) {
    float hv = bf2f(hr[i]);
    a0 = fmaf(hv, Wu[i * 2 + 0], a0);
    a1 = fmaf(hv, Wu[i * 2 + 1], a1);
  }
  #pragma unroll
  for (int off = 32; off; off >>= 1) {
    a0 += __shfl_xor(a0, off, 64);
    a1 += __shfl_xor(a1, off, 64);
  }
  int lane = threadIdx.x & 63, wid = threadIdx.x >> 6;
  if (lane == 0) { sm[wid] = a0; sm[4 + wid] = a1; }
  __syncthreads();
  if (threadIdx.x == 0) {
    out[row * 2 + 0] = sm[0] + sm[1] + sm[2] + sm[3] + bu[0];
    out[row * 2 + 1] = sm[4] + sm[5] + sm[6] + sm[7] + bu[1];
  }
}

// ============================ launcher ============================
static inline void launch_gemm(hipStream_t stream, int N,
    const short* A, long sAb, long sAt, long sAh,
    const short* B, long sBh, long sBd,
    void* C, long sCb, long sCt, long sCh,
    const float* bias, const float* res, int K, float alpha, int alphaN,
    int relu, int cbf16) {
  GemmP p;
  p.A = A; p.B = B; p.C = C; p.bias = bias; p.res = res;
  p.sAb = sAb; p.sAt = sAt; p.sAh = sAh;
  p.sBh = sBh; p.sBd = sBd;
  p.sCb = sCb; p.sCt = sCt; p.sCh = sCh;
  p.K = K; p.alpha = alpha; p.alphaN = alphaN; p.gridx = N / 256;
  p.relu = relu; p.cbf16 = cbf16;
  p.hasbias = bias != nullptr; p.hasres = res != nullptr;
  int nwg = (N / 256) * ((NB * T_SEQ) / 128);
  gemm_bf16<<<nwg, 512, 147456, stream>>>(p);
}

extern "C" void kernel_launch(void* const* d_in, const int* in_sizes, int n_in,
                              void* d_out, int out_size, void* d_ws, size_t ws_size,
                              hipStream_t stream) {
  const int*   tokens = (const int*)d_in[0];
  const float* emb_w  = (const float*)d_in[1];
  const float* pos_w  = (const float*)d_in[2];
  const float* Wq     = (const float*)d_in[3];
  const float* Wk     = (const float*)d_in[4];
  const float* Wv     = (const float*)d_in[5];
  const float* Wo     = (const float*)d_in[6];
  const float* ln1_g  = (const float*)d_in[7];
  const float* ln1_b  = (const float*)d_in[8];
  const float* W1     = (const float*)d_in[9];
  const float* b1     = (const float*)d_in[10];
  const float* W2     = (const float*)d_in[11];
  const float* b2     = (const float*)d_in[12];
  const float* ln2_g  = (const float*)d_in[13];
  const float* ln2_b  = (const float*)d_in[14];
  const float* lnf_g  = (const float*)d_in[15];
  const float* lnf_b  = (const float*)d_in[16];
  const float* Wu     = (const float*)d_in[17];
  const float* bu     = (const float*)d_in[18];
  float* out = (float*)d_out;

  // ---- workspace layout (bytes) ----
  char* ws = (char*)d_ws;
  float* X     = (float*)(ws);                       // 32 MB f32 [B,T,E]
  short* Hb    = (short*)(ws + 33554432);            // 16 MB bf16 (LN out / attn out)
  short* QKVb  = (short*)(ws + 50331648);            // 48 MB bf16 [B][3][H][T][DH]
  short* FFH   = (short*)(ws + 100663296);           // 64 MB bf16 [8192,4096]
  short* WqkvT = (short*)(ws + 167772160);           // 6 MB  [3][16][64][1024]
  short* WoT   = (short*)(ws + 174063616);           // 2 MB  [1024][1024]
  short* W1T   = (short*)(ws + 176160768);           // 8 MB  [4096][1024]
  short* W2T   = (short*)(ws + 184549376);           // 8 MB  [1024][4096]

  const float scale = 0.022097086912079608f;         // 1/sqrt(2048)

  embed_kernel<<<32768, 256, 0, stream>>>(tokens, emb_w, pos_w, X);

  for (int l = 0; l < NLAYER; ++l) {
    PrepP pp;
    pp.s0 = Wq + (size_t)l * 1048576; pp.d0 = WqkvT;
    pp.s1 = Wk + (size_t)l * 1048576; pp.d1 = WqkvT + 1048576;
    pp.s2 = Wv + (size_t)l * 1048576; pp.d2 = WqkvT + 2097152;
    pp.s3 = Wo + (size_t)l * 1048576; pp.d3 = WoT;
    pp.s4 = W1 + (size_t)l * 4194304; pp.d4 = W1T;
    pp.s5 = W2 + (size_t)l * 4194304; pp.d5 = W2T;
    prep_kernel<<<12288, dim3(32, 8), 0, stream>>>(pp);

    ln_bf16_kernel<<<8192, 256, 0, stream>>>(X, ln1_g + l * 1024, ln1_b + l * 1024, Hb);

    // merged QKV: N = 3072, C -> [b][3][h][t][d]; Q cols pre-scaled
    launch_gemm(stream, 3072, Hb, 2097152, 1024, 64, WqkvT, 65536, 1024,
                QKVb, 6291456, 64, 131072, nullptr, nullptr, 1024, scale, 1024, 0, 1);

    attn_mfma_kernel<<<512, 512, 0, stream>>>(QKVb, Hb);   // att -> Hb

    // Wo: A=att [B,H,T,DH], C=X f32 (+res X)
    launch_gemm(stream, 1024, Hb, 2097152, 64, 131072, WoT, 65536, 1024,
                X, 2097152, 1024, 64, nullptr, X, 1024, 1.0f, 0, 0, 0);

    ln_bf16_kernel<<<8192, 256, 0, stream>>>(X, ln2_g + l * 1024, ln2_b + l * 1024, Hb);

    launch_gemm(stream, 4096, Hb, 2097152, 1024, 64, W1T, 65536, 1024,
                FFH, 8388608, 4096, 64, b1 + (size_t)l * 4096, nullptr, 1024, 1.0f, 0, 1, 1);
    launch_gemm(stream, 1024, FFH, 8388608, 4096, 64, W2T, 262144, 4096,
                X, 2097152, 1024, 64, b2 + (size_t)l * 1024, X, 4096, 1.0f, 0, 0, 0);
  }

  ln_bf16_kernel<<<8192, 256, 0, stream>>>(X, lnf_g, lnf_b, Hb);
  head_kernel<<<8192, 256, 0, stream>>>(Hb, Wu, bu, out);
}

// Round 19
// 2966.600 us; speedup vs baseline: 1.0523x; 1.0269x over previous
//
#include <hip/hip_runtime.h>
#include <hip/hip_bf16.h>
#include <math.h>

#define E_DIM 1024
#define T_SEQ 2048
#define NH 16
#define DHEAD 64
#define NB 4
#define NLAYER 8

typedef __attribute__((ext_vector_type(8))) short bf16x8;
typedef __attribute__((ext_vector_type(4))) short short4v;
typedef __attribute__((ext_vector_type(4))) float f32x4;

#if __has_builtin(__builtin_amdgcn_exp2f)
#define EXP2(x) __builtin_amdgcn_exp2f(x)
#else
#define EXP2(x) exp2f(x)
#endif

static __device__ __forceinline__ short f2bf(float f) {
  union { __hip_bfloat16 h; short s; } u;
  u.h = __float2bfloat16(f);
  return u.s;
}
static __device__ __forceinline__ float bf2f(short s) {
  union { unsigned u; float f; } v;
  v.u = ((unsigned)(unsigned short)s) << 16;
  return v.f;
}

// async global->LDS, 16B per lane; LDS dest is wave-uniform base + lane*16.
static __device__ __forceinline__ void gload16(const short* g, short* l) {
  __builtin_amdgcn_global_load_lds(
      (const __attribute__((address_space(1))) unsigned*)(g),
      (__attribute__((address_space(3))) unsigned*)(l), 16, 0, 0);
}

// XCD-aware bijective block swizzle (valid when nwg % 8 == 0).
static __device__ __forceinline__ int xcd_swz(int orig, int nwg) {
  return (orig & 7) * (nwg >> 3) + (orig >> 3);
}

// ============================ embedding (f32) ============================
__global__ __launch_bounds__(256) void embed_kernel(const int* __restrict__ tokens,
    const float* __restrict__ emb, const float* __restrict__ pos, float* __restrict__ x) {
  int idx = blockIdx.x * 256 + threadIdx.x;
  int bt = idx >> 10;
  int e  = idx & 1023;
  int t  = bt & (T_SEQ - 1);
  int tok = tokens[bt];
  x[idx] = emb[tok * E_DIM + e] + pos[t * E_DIM + e];
}

// ============================ layernorm f32 -> bf16 ============================
__global__ __launch_bounds__(256) void ln_bf16_kernel(const float* __restrict__ x,
    const float* __restrict__ g, const float* __restrict__ b, short* __restrict__ out) {
  __shared__ float s1[4], s2[4];
  int row = blockIdx.x;
  const float4* xr = (const float4*)(x + (size_t)row * E_DIM);
  float4 xv = xr[threadIdx.x];
  float s = xv.x + xv.y + xv.z + xv.w;
  float q = xv.x*xv.x + xv.y*xv.y + xv.z*xv.z + xv.w*xv.w;
  #pragma unroll
  for (int off = 32; off; off >>= 1) {
    s += __shfl_xor(s, off, 64);
    q += __shfl_xor(q, off, 64);
  }
  int lane = threadIdx.x & 63, wid = threadIdx.x >> 6;
  if (lane == 0) { s1[wid] = s; s2[wid] = q; }
  __syncthreads();
  float mean = (s1[0] + s1[1] + s1[2] + s1[3]) * (1.0f / E_DIM);
  float ms   = (s2[0] + s2[1] + s2[2] + s2[3]) * (1.0f / E_DIM);
  float rstd = rsqrtf(ms - mean * mean + 1e-5f);
  float4 gv = ((const float4*)g)[threadIdx.x];
  float4 bv = ((const float4*)b)[threadIdx.x];
  short4v ov;
  ov.x = f2bf((xv.x - mean) * rstd * gv.x + bv.x);
  ov.y = f2bf((xv.y - mean) * rstd * gv.y + bv.y);
  ov.z = f2bf((xv.z - mean) * rstd * gv.z + bv.z);
  ov.w = f2bf((xv.w - mean) * rstd * gv.w + bv.w);
  *(short4v*)(out + (size_t)row * E_DIM + threadIdx.x * 4) = ov;
}

// ============================ merged per-layer weight prep ============================
struct PrepP {
  const float *s0, *s1, *s2, *s3, *s4, *s5;
  short *d0, *d1, *d2, *d3, *d4, *d5;
};

__global__ void prep_kernel(PrepP p) {
  __shared__ float tile[32][33];
  int bid = blockIdx.x;
  const float* src; short* dst; int K, N, kb, local;
  if (bid < 1024)      { src = p.s0; dst = p.d0; K = 1024; N = 64;   kb = 32;  local = bid; }
  else if (bid < 2048) { src = p.s1; dst = p.d1; K = 1024; N = 64;   kb = 32;  local = bid - 1024; }
  else if (bid < 3072) { src = p.s2; dst = p.d2; K = 1024; N = 64;   kb = 32;  local = bid - 2048; }
  else if (bid < 4096) { src = p.s3; dst = p.d3; K = 1024; N = 1024; kb = 32;  local = bid - 3072; }
  else if (bid < 8192) { src = p.s4; dst = p.d4; K = 1024; N = 4096; kb = 32;  local = bid - 4096; }
  else                 { src = p.s5; dst = p.d5; K = 4096; N = 1024; kb = 128; local = bid - 8192; }
  int per = kb * (N >> 5);
  int z = local / per, rem = local % per;
  int k0 = (rem % kb) * 32, n0 = (rem / kb) * 32;
  src += (size_t)z * K * N;
  dst += (size_t)z * N * K;
  int tx = threadIdx.x, ty = threadIdx.y;
  #pragma unroll
  for (int i = 0; i < 4; ++i)
    tile[ty + 8 * i][tx] = src[(size_t)(k0 + ty + 8 * i) * N + n0 + tx];
  __syncthreads();
  #pragma unroll
  for (int i = 0; i < 4; ++i)
    dst[(size_t)(n0 + ty + 8 * i) * K + k0 + tx] = f2bf(tile[tx][ty + 8 * i]);
}

// ============================ bf16 MFMA GEMM: 128x256, tri-buffer, counted vmcnt(6) ============================
// (round-10 structure — frozen)
struct GemmP {
  const short* A; const short* B; void* C;
  const float* bias; const float* res;
  long sAb, sAt, sAh;       // m>>11, m&2047, k>>6 (k&63 stride 1)
  long sBh, sBd;            // n>>6, n&63 (k stride 1)
  long sCb, sCt, sCh;       // m>>11, m&2047, n>>6 (n&63 stride 1)
  int K; float alpha; int alphaN; int gridx;
  int relu; int cbf16; int hasbias; int hasres;
};

__global__ __launch_bounds__(512, 1) void gemm_bf16(GemmP p) {
  extern __shared__ __align__(16) short Lsh[];
  constexpr int ASZ  = 128 * 64;          // 8192 shorts (16KB)
  constexpr int SLOT = ASZ + 256 * 64;    // + 16384 shorts (32KB) = 48KB/slot

  const int t = threadIdx.x;
  const int lane = t & 63, wid = t >> 6;
  const int wm = wid >> 2, wn = wid & 3;
  const int rA = lane & 15, g = lane >> 4;
  const int wg = xcd_swz(blockIdx.x, gridDim.x);
  const long bm = (long)(wg / p.gridx) * 128, bn = (long)(wg % p.gridx) * 256;

  const int srow8 = lane >> 3;
  const int schunk = (lane & 7) ^ srow8;
  const short* aS[2]; const short* bS[4];
  #pragma unroll
  for (int i = 0; i < 2; ++i) {
    long m = bm + i * 64 + wid * 8 + srow8;
    aS[i] = p.A + (m >> 11) * p.sAb + (m & 2047) * p.sAt + schunk * 8;
  }
  #pragma unroll
  for (int i = 0; i < 4; ++i) {
    long n = bn + i * 64 + wid * 8 + srow8;
    bS[i] = p.B + (n >> 6) * p.sBh + (n & 63) * p.sBd + schunk * 8;
  }
  const int dOff = wid * 512;

#define ISSUE_TILE(slot)                                                      \
  {                                                                           \
    short* sb = Lsh + (slot) * SLOT;                                          \
    _Pragma("unroll")                                                         \
    for (int i = 0; i < 2; ++i) { gload16(aS[i], sb + i * 4096 + dOff); aS[i] += p.sAh; } \
    _Pragma("unroll")                                                         \
    for (int i = 0; i < 4; ++i) { gload16(bS[i], sb + ASZ + i * 4096 + dOff); bS[i] += 64; } \
  }

  f32x4 acc[4][4] = {};
  const int NT = p.K >> 6;

  ISSUE_TILE(0)
  ISSUE_TILE(1)
  asm volatile("s_waitcnt vmcnt(6)" ::: "memory");
  __builtin_amdgcn_s_barrier();

  int rd = 0;
  for (int kt = 0; kt < NT; ++kt) {
    const int wr2 = rd + 2 >= 3 ? rd - 1 : rd + 2;
    if (kt + 2 < NT) ISSUE_TILE(wr2)
    const short* sb = Lsh + rd * SLOT;
    bf16x8 af[4][2], bf[4][2];
    #pragma unroll
    for (int kk = 0; kk < 2; ++kk) {
      const int ch = ((g + kk * 4) ^ (rA & 7)) * 8;
      #pragma unroll
      for (int f = 0; f < 4; ++f) {
        af[f][kk] = *(const bf16x8*)&sb[(wm * 64 + f * 16 + rA) * 64 + ch];
        bf[f][kk] = *(const bf16x8*)&sb[ASZ + (wn * 64 + f * 16 + rA) * 64 + ch];
      }
    }
    asm volatile("s_waitcnt lgkmcnt(0)" ::: "memory");
    __builtin_amdgcn_sched_barrier(0);
    __builtin_amdgcn_s_setprio(1);
    #pragma unroll
    for (int kk = 0; kk < 2; ++kk)
      #pragma unroll
      for (int i = 0; i < 4; ++i)
        #pragma unroll
        for (int j = 0; j < 4; ++j)
          acc[i][j] = __builtin_amdgcn_mfma_f32_16x16x32_bf16(af[i][kk], bf[j][kk], acc[i][j], 0, 0, 0);
    __builtin_amdgcn_s_setprio(0);
    if (kt + 1 < NT) {
      if (kt + 2 < NT) { asm volatile("s_waitcnt vmcnt(6)" ::: "memory"); }
      else             { asm volatile("s_waitcnt vmcnt(0)" ::: "memory"); }
      __builtin_amdgcn_s_barrier();
    }
    rd = rd + 1 >= 3 ? 0 : rd + 1;
  }
#undef ISSUE_TILE

  float bias4[4], aa4[4];
  long ncol[4];
  #pragma unroll
  for (int j = 0; j < 4; ++j) {
    long n = bn + wn * 64 + j * 16 + rA;
    ncol[j] = (n >> 6) * p.sCh + (n & 63);
    bias4[j] = p.hasbias ? p.bias[n] : 0.f;
    aa4[j] = (n < p.alphaN) ? p.alpha : 1.0f;
  }
  #pragma unroll
  for (int i = 0; i < 4; ++i) {
    #pragma unroll
    for (int r = 0; r < 4; ++r) {
      long m = bm + wm * 64 + i * 16 + g * 4 + r;
      long mb = (m >> 11) * p.sCb + (m & 2047) * p.sCt;
      #pragma unroll
      for (int j = 0; j < 4; ++j) {
        long ca = mb + ncol[j];
        float v = aa4[j] * acc[i][j][r] + bias4[j];
        if (p.relu) v = fmaxf(v, 0.f);
        if (p.hasres) v += p.res[ca];
        if (p.cbf16) ((short*)p.C)[ca] = f2bf(v);
        else ((float*)p.C)[ca] = v;
      }
    }
  }
}

// ============================ MFMA flash attention v8: 4 q-tiles per wave ============================
// r18 mechanism scaled: each wave owns FOUR q-tiles (+0/+128/+256/+384). K/V
// fragments read from LDS once feed 4 MFMA chains (reads/MFMA quarter), 4
// independent EXP2 chains interleave. Grid 256 (1 block/CU), dyn-LDS 80KB.
__global__ __launch_bounds__(512, 1) void attn_mfma_kernel(const short* __restrict__ qkv,
                                                           short* __restrict__ att) {
  extern __shared__ __align__(16) short Ash[];
  short* Ks = Ash;                 // 4096 shorts (8KB), swizzled rows
  short* Vt = Ash + 4096;          // 4096 shorts (8KB), skewed transpose
  short* Pq = Ash + 8192;          // 8 waves x 4 tiles x 1024 shorts (64KB)

  const int t = threadIdx.x;
  const int lane = t & 63, wid = t >> 6;
  const int wg = xcd_swz(blockIdx.x, gridDim.x);
  const int bh = wg >> 2;                   // 64 (b,h) groups, 4 q-blocks of 512
  const int b = bh >> 4, h = bh & 15;
  const int q0blk = (wg & 3) * 512;
  const int rA = lane & 15;
  const int g  = lane >> 4;
  const int xq = (rA & 7) << 3;
  const float L2E = 1.4426950408889634f;

  const short* Qg = qkv + (size_t)b * 6291456 + (size_t)h * 131072;
  const short* Kg = Qg + 2097152;
  const short* Vg = Qg + 4194304;

  const int qA = q0blk + wid * 16;
  const int qB = qA + 128;
  const int qC = qA + 256;
  const int qD = qA + 384;
  bf16x8 qfA0 = *(const bf16x8*)(Qg + (size_t)(qA + rA) * DHEAD + g * 8);
  bf16x8 qfA1 = *(const bf16x8*)(Qg + (size_t)(qA + rA) * DHEAD + 32 + g * 8);
  bf16x8 qfB0 = *(const bf16x8*)(Qg + (size_t)(qB + rA) * DHEAD + g * 8);
  bf16x8 qfB1 = *(const bf16x8*)(Qg + (size_t)(qB + rA) * DHEAD + 32 + g * 8);
  bf16x8 qfC0 = *(const bf16x8*)(Qg + (size_t)(qC + rA) * DHEAD + g * 8);
  bf16x8 qfC1 = *(const bf16x8*)(Qg + (size_t)(qC + rA) * DHEAD + 32 + g * 8);
  bf16x8 qfD0 = *(const bf16x8*)(Qg + (size_t)(qD + rA) * DHEAD + g * 8);
  bf16x8 qfD1 = *(const bf16x8*)(Qg + (size_t)(qD + rA) * DHEAD + 32 + g * 8);

  bf16x8 ones;
  #pragma unroll
  for (int j = 0; j < 8; ++j) ones[j] = (short)0x3F80;   // bf16 1.0

  short* PwA = Pq + wid * 4096;
  short* PwB = PwA + 1024;
  short* PwC = PwA + 2048;
  short* PwD = PwA + 3072;
  const int ss = t >> 3, sp = t & 7;

  f32x4 lrunA = {}, lrunB = {}, lrunC = {}, lrunD = {};
  f32x4 accoA[4] = {}, accoB[4] = {}, accoC[4] = {}, accoD[4] = {};

  bf16x8 kreg = *(const bf16x8*)(Kg + (size_t)ss * DHEAD + sp * 8);
  bf16x8 vreg = *(const bf16x8*)(Vg + (size_t)ss * DHEAD + sp * 8);

  for (int tile = 0; tile < T_SEQ / 64; ++tile) {
    __syncthreads();
    *(bf16x8*)&Ks[ss * 64 + ((sp ^ (ss & 7)) << 3)] = kreg;
    #pragma unroll
    for (int j = 0; j < 8; ++j) {
      int d = sp * 8 + j;
      Vt[d * 64 + ((ss + 8 * (sp + j)) & 63)] = vreg[j];
    }
    __syncthreads();
    if (tile + 1 < T_SEQ / 64) {
      kreg = *(const bf16x8*)(Kg + (size_t)((tile + 1) * 64 + ss) * DHEAD + sp * 8);
      vreg = *(const bf16x8*)(Vg + (size_t)((tile + 1) * 64 + ss) * DHEAD + sp * 8);
    }

    // ---- QK^T for 4 q-tiles; K fragments read once, used 4x ----
    f32x4 accsA[4], accsB[4], accsC[4], accsD[4];
    __builtin_amdgcn_s_setprio(1);
    #pragma unroll
    for (int st = 0; st < 4; ++st) {
      int srow = st * 16 + rA;
      bf16x8 kf0 = *(const bf16x8*)&Ks[srow * 64 + ((g ^ (rA & 7)) << 3)];
      bf16x8 kf1 = *(const bf16x8*)&Ks[srow * 64 + (((g + 4) ^ (rA & 7)) << 3)];
      f32x4 zA = {}, zB = {}, zC = {}, zD = {};
      zA = __builtin_amdgcn_mfma_f32_16x16x32_bf16(kf0, qfA0, zA, 0, 0, 0);
      zB = __builtin_amdgcn_mfma_f32_16x16x32_bf16(kf0, qfB0, zB, 0, 0, 0);
      zC = __builtin_amdgcn_mfma_f32_16x16x32_bf16(kf0, qfC0, zC, 0, 0, 0);
      zD = __builtin_amdgcn_mfma_f32_16x16x32_bf16(kf0, qfD0, zD, 0, 0, 0);
      accsA[st] = __builtin_amdgcn_mfma_f32_16x16x32_bf16(kf1, qfA1, zA, 0, 0, 0);
      accsB[st] = __builtin_amdgcn_mfma_f32_16x16x32_bf16(kf1, qfB1, zB, 0, 0, 0);
      accsC[st] = __builtin_amdgcn_mfma_f32_16x16x32_bf16(kf1, qfC1, zC, 0, 0, 0);
      accsD[st] = __builtin_amdgcn_mfma_f32_16x16x32_bf16(kf1, qfD1, zD, 0, 0, 0);
    }
    __builtin_amdgcn_s_setprio(0);

    // ---- no-max softmax numerators, 4 independent chains ----
    #pragma unroll
    for (int st = 0; st < 4; ++st) {
      short4v pkA, pkB, pkC, pkD;
      pkA.x = f2bf(EXP2(accsA[st][0] * L2E));
      pkA.y = f2bf(EXP2(accsA[st][1] * L2E));
      pkA.z = f2bf(EXP2(accsA[st][2] * L2E));
      pkA.w = f2bf(EXP2(accsA[st][3] * L2E));
      pkB.x = f2bf(EXP2(accsB[st][0] * L2E));
      pkB.y = f2bf(EXP2(accsB[st][1] * L2E));
      pkB.z = f2bf(EXP2(accsB[st][2] * L2E));
      pkB.w = f2bf(EXP2(accsB[st][3] * L2E));
      pkC.x = f2bf(EXP2(accsC[st][0] * L2E));
      pkC.y = f2bf(EXP2(accsC[st][1] * L2E));
      pkC.z = f2bf(EXP2(accsC[st][2] * L2E));
      pkC.w = f2bf(EXP2(accsC[st][3] * L2E));
      pkD.x = f2bf(EXP2(accsD[st][0] * L2E));
      pkD.y = f2bf(EXP2(accsD[st][1] * L2E));
      pkD.z = f2bf(EXP2(accsD[st][2] * L2E));
      pkD.w = f2bf(EXP2(accsD[st][3] * L2E));
      const int po = (rA * 64 + st * 16 + g * 4) ^ xq;
      *(short4v*)&PwA[po] = pkA;
      *(short4v*)&PwB[po] = pkB;
      *(short4v*)&PwC[po] = pkC;
      *(short4v*)&PwD[po] = pkD;
    }
    asm volatile("s_waitcnt lgkmcnt(0)" ::: "memory");

    // ---- PV for 4 tiles; V fragments read once, used 4x ----
    __builtin_amdgcn_s_setprio(1);
    #pragma unroll
    for (int sk = 0; sk < 2; ++sk) {
      const int po = (rA * 64 + sk * 32 + g * 8) ^ xq;
      bf16x8 pfA = *(const bf16x8*)&PwA[po];
      bf16x8 pfB = *(const bf16x8*)&PwB[po];
      bf16x8 pfC = *(const bf16x8*)&PwC[po];
      bf16x8 pfD = *(const bf16x8*)&PwD[po];
      lrunA = __builtin_amdgcn_mfma_f32_16x16x32_bf16(pfA, ones, lrunA, 0, 0, 0);
      lrunB = __builtin_amdgcn_mfma_f32_16x16x32_bf16(pfB, ones, lrunB, 0, 0, 0);
      lrunC = __builtin_amdgcn_mfma_f32_16x16x32_bf16(pfC, ones, lrunC, 0, 0, 0);
      lrunD = __builtin_amdgcn_mfma_f32_16x16x32_bf16(pfD, ones, lrunD, 0, 0, 0);
      #pragma unroll
      for (int dt = 0; dt < 4; ++dt) {
        int d = dt * 16 + rA;
        bf16x8 vf = *(const bf16x8*)&Vt[d * 64 +
            ((sk * 32 + g * 8 + 8 * (dt * 2 + (rA >> 3) + (rA & 7))) & 63)];
        accoA[dt] = __builtin_amdgcn_mfma_f32_16x16x32_bf16(pfA, vf, accoA[dt], 0, 0, 0);
        accoB[dt] = __builtin_amdgcn_mfma_f32_16x16x32_bf16(pfB, vf, accoB[dt], 0, 0, 0);
        accoC[dt] = __builtin_amdgcn_mfma_f32_16x16x32_bf16(pfC, vf, accoC[dt], 0, 0, 0);
        accoD[dt] = __builtin_amdgcn_mfma_f32_16x16x32_bf16(pfD, vf, accoD[dt], 0, 0, 0);
      }
    }
    __builtin_amdgcn_s_setprio(0);
  }

  float lA[4], lB[4], lC[4], lD[4];
  #pragma unroll
  for (int r = 0; r < 4; ++r) {
    lA[r] = 1.0f / lrunA[r]; lB[r] = 1.0f / lrunB[r];
    lC[r] = 1.0f / lrunC[r]; lD[r] = 1.0f / lrunD[r];
  }
  const size_t obase = (size_t)bh * T_SEQ * DHEAD;
  #pragma unroll
  for (int dt = 0; dt < 4; ++dt)
    #pragma unroll
    for (int r = 0; r < 4; ++r) {
      att[obase + (size_t)(qA + g * 4 + r) * DHEAD + dt * 16 + rA] = f2bf(accoA[dt][r] * lA[r]);
      att[obase + (size_t)(qB + g * 4 + r) * DHEAD + dt * 16 + rA] = f2bf(accoB[dt][r] * lB[r]);
      att[obase + (size_t)(qC + g * 4 + r) * DHEAD + dt * 16 + rA] = f2bf(accoC[dt][r] * lC[r]);
      att[obase + (size_t)(qD + g * 4 + r) * DHEAD + dt * 16 + rA] = f2bf(accoD[dt][r] * lD[r]);
    }
}

// ============================ head ============================
__global__ __launch_bounds__(256) void head_kernel(const short* __restrict__ h,
    const float* __restrict__ Wu, const float* __restrict__ bu, float* __restrict__ out) {
  __shared__ float sm[8];
  int row = blockIdx.x;
  const short* hr = h + (size_t)row * E_DIM;
  float a0 = 0.f, a1 = 0.f;
  for (int i = threadIdx.x; i < E_DIM; i += 256) {
    float hv = bf2f(hr[i]);
    a0 = fmaf(hv, Wu[i * 2 + 0], a0);
    a1 = fmaf(hv, Wu[i * 2 + 1], a1);
  }
  #pragma unroll
  for (int off = 32; off; off >>= 1) {
    a0 += __shfl_xor(a0, off, 64);
    a1 += __shfl_xor(a1, off, 64);
  }
  int lane = threadIdx.x & 63, wid = threadIdx.x >> 6;
  if (lane == 0) { sm[wid] = a0; sm[4 + wid] = a1; }
  __syncthreads();
  if (threadIdx.x == 0) {
    out[row * 2 + 0] = sm[0] + sm[1] + sm[2] + sm[3] + bu[0];
    out[row * 2 + 1] = sm[4] + sm[5] + sm[6] + sm[7] + bu[1];
  }
}

// ============================ launcher ============================
static inline void launch_gemm(hipStream_t stream, int N,
    const short* A, long sAb, long sAt, long sAh,
    const short* B, long sBh, long sBd,
    void* C, long sCb, long sCt, long sCh,
    const float* bias, const float* res, int K, float alpha, int alphaN,
    int relu, int cbf16) {
  GemmP p;
  p.A = A; p.B = B; p.C = C; p.bias = bias; p.res = res;
  p.sAb = sAb; p.sAt = sAt; p.sAh = sAh;
  p.sBh = sBh; p.sBd = sBd;
  p.sCb = sCb; p.sCt = sCt; p.sCh = sCh;
  p.K = K; p.alpha = alpha; p.alphaN = alphaN; p.gridx = N / 256;
  p.relu = relu; p.cbf16 = cbf16;
  p.hasbias = bias != nullptr; p.hasres = res != nullptr;
  int nwg = (N / 256) * ((NB * T_SEQ) / 128);
  gemm_bf16<<<nwg, 512, 147456, stream>>>(p);
}

extern "C" void kernel_launch(void* const* d_in, const int* in_sizes, int n_in,
                              void* d_out, int out_size, void* d_ws, size_t ws_size,
                              hipStream_t stream) {
  const int*   tokens = (const int*)d_in[0];
  const float* emb_w  = (const float*)d_in[1];
  const float* pos_w  = (const float*)d_in[2];
  const float* Wq     = (const float*)d_in[3];
  const float* Wk     = (const float*)d_in[4];
  const float* Wv     = (const float*)d_in[5];
  const float* Wo     = (const float*)d_in[6];
  const float* ln1_g  = (const float*)d_in[7];
  const float* ln1_b  = (const float*)d_in[8];
  const float* W1     = (const float*)d_in[9];
  const float* b1     = (const float*)d_in[10];
  const float* W2     = (const float*)d_in[11];
  const float* b2     = (const float*)d_in[12];
  const float* ln2_g  = (const float*)d_in[13];
  const float* ln2_b  = (const float*)d_in[14];
  const float* lnf_g  = (const float*)d_in[15];
  const float* lnf_b  = (const float*)d_in[16];
  const float* Wu     = (const float*)d_in[17];
  const float* bu     = (const float*)d_in[18];
  float* out = (float*)d_out;

  // ---- workspace layout (bytes) ----
  char* ws = (char*)d_ws;
  float* X     = (float*)(ws);                       // 32 MB f32 [B,T,E]
  short* Hb    = (short*)(ws + 33554432);            // 16 MB bf16 (LN out / attn out)
  short* QKVb  = (short*)(ws + 50331648);            // 48 MB bf16 [B][3][H][T][DH]
  short* FFH   = (short*)(ws + 100663296);           // 64 MB bf16 [8192,4096]
  short* WqkvT = (short*)(ws + 167772160);           // 6 MB  [3][16][64][1024]
  short* WoT   = (short*)(ws + 174063616);           // 2 MB  [1024][1024]
  short* W1T   = (short*)(ws + 176160768);           // 8 MB  [4096][1024]
  short* W2T   = (short*)(ws + 184549376);           // 8 MB  [1024][4096]

  const float scale = 0.022097086912079608f;         // 1/sqrt(2048)

  embed_kernel<<<32768, 256, 0, stream>>>(tokens, emb_w, pos_w, X);

  for (int l = 0; l < NLAYER; ++l) {
    PrepP pp;
    pp.s0 = Wq + (size_t)l * 1048576; pp.d0 = WqkvT;
    pp.s1 = Wk + (size_t)l * 1048576; pp.d1 = WqkvT + 1048576;
    pp.s2 = Wv + (size_t)l * 1048576; pp.d2 = WqkvT + 2097152;
    pp.s3 = Wo + (size_t)l * 1048576; pp.d3 = WoT;
    pp.s4 = W1 + (size_t)l * 4194304; pp.d4 = W1T;
    pp.s5 = W2 + (size_t)l * 4194304; pp.d5 = W2T;
    prep_kernel<<<12288, dim3(32, 8), 0, stream>>>(pp);

    ln_bf16_kernel<<<8192, 256, 0, stream>>>(X, ln1_g + l * 1024, ln1_b + l * 1024, Hb);

    // merged QKV: N = 3072, C -> [b][3][h][t][d]; Q cols pre-scaled
    launch_gemm(stream, 3072, Hb, 2097152, 1024, 64, WqkvT, 65536, 1024,
                QKVb, 6291456, 64, 131072, nullptr, nullptr, 1024, scale, 1024, 0, 1);

    attn_mfma_kernel<<<256, 512, 81920, stream>>>(QKVb, Hb);   // att -> Hb

    // Wo: A=att [B,H,T,DH], C=X f32 (+res X)
    launch_gemm(stream, 1024, Hb, 2097152, 64, 131072, WoT, 65536, 1024,
                X, 2097152, 1024, 64, nullptr, X, 1024, 1.0f, 0, 0, 0);

    ln_bf16_kernel<<<8192, 256, 0, stream>>>(X, ln2_g + l * 1024, ln2_b + l * 1024, Hb);

    launch_gemm(stream, 4096, Hb, 2097152, 1024, 64, W1T, 65536, 1024,
                FFH, 8388608, 4096, 64, b1 + (size_t)l * 4096, nullptr, 1024, 1.0f, 0, 1, 1);
    launch_gemm(stream, 1024, FFH, 8388608, 4096, 64, W2T, 262144, 4096,
                X, 2097152, 1024, 64, b2 + (size_t)l * 1024, X, 4096, 1.0f, 0, 0, 0);
  }

  ln_bf16_kernel<<<8192, 256, 0, stream>>>(X, lnf_g, lnf_b, Hb);
  head_kernel<<<8192, 256, 0, stream>>>(Hb, Wu, bu, out);
}